// Round 3
// baseline (5283.797 us; speedup 1.0000x reference)
//
#include <hip/hip_runtime.h>
#include <math.h>

typedef __bf16 bf16;
typedef __bf16 bf16x8 __attribute__((ext_vector_type(8)));
typedef __bf16 bf16x4 __attribute__((ext_vector_type(4)));
typedef float  f32x4  __attribute__((ext_vector_type(4)));

#define SEQ   1570
#define NB    4
#define NF    8
#define NT    196
#define DM    512
#define MR    (NB*SEQ)   // 6280 rows
#define SPCH  13         // special-attn key chunks of 128

// ---------------------------------------------------------------------------
// Rotary tables
// ---------------------------------------------------------------------------
__global__ void build_rot_k(float* fsin, float* fcos, float* isin, float* icos)
{
    int tid = blockIdx.x * blockDim.x + threadIdx.x;
    if (tid < NF * 32) {
        int fi = tid >> 5, i = tid & 31;
        float inv = powf(10000.f, -(2.f * i) / 64.f);
        float v = fi * inv;
        float s = sinf(v), c = cosf(v);
        fsin[fi*64 + 2*i] = s; fsin[fi*64 + 2*i + 1] = s;
        fcos[fi*64 + 2*i] = c; fcos[fi*64 + 2*i + 1] = c;
    }
    if (tid < NT * 32) {
        int t = tid >> 5, i = tid & 31;
        int hi = t / 14, wi = t % 14;
        const float PI = 3.14159265358979323846f;
        float v;
        if (i < 16) {
            float scale = 1.f + 4.f * i / 15.f;
            v = (-1.f + 2.f * hi / 13.f) * scale * PI;
        } else {
            float scale = 1.f + 4.f * (i - 16) / 15.f;
            v = (-1.f + 2.f * wi / 13.f) * scale * PI;
        }
        float s = sinf(v), c = cosf(v);
        isin[t*64 + 2*i] = s; isin[t*64 + 2*i + 1] = s;
        icos[t*64 + 2*i] = c; icos[t*64 + 2*i + 1] = c;
    }
}

// ---------------------------------------------------------------------------
// Patchify: video (4,8,3,224,224) f32 -> VP (6272,768) bf16
// ---------------------------------------------------------------------------
__global__ void patch_gather_k(const float* __restrict__ video, bf16* __restrict__ VP)
{
    int idx = blockIdx.x * blockDim.x + threadIdx.x;
    if (idx >= NB * NF * NT * 768) return;
    int kk  = idx % 768;
    int row = (idx / 768) % (NF * NT);
    int b   = idx / (768 * NF * NT);
    int ch = kk % 3, pp = kk / 3;
    int pr = pp >> 4, pc = pp & 15;
    int fi = row / NT, t = row % NT;
    int hi = t / 14, wi = t % 14;
    size_t src = ((((size_t)b * NF + fi) * 3 + ch) * 224 + (hi*16 + pr)) * 224 + (wi*16 + pc);
    VP[idx] = (bf16)video[src];
}

// ---------------------------------------------------------------------------
// cls token + action-angle rows (fp32 X)
// ---------------------------------------------------------------------------
__global__ void init_special_k(float* X, const float* __restrict__ cls,
                               const float* __restrict__ aa_w,
                               const float* __restrict__ aa_W,
                               const float* __restrict__ aa_b)
{
    int idx = blockIdx.x * blockDim.x + threadIdx.x;
    if (idx >= NB * DM) return;
    int b = idx >> 9, d = idx & 511;
    X[(size_t)b * SEQ * DM + d] = cls[d];
    float acc = aa_b[d];
    for (int i = 0; i < 18; ++i) acc += aa_w[b*18 + i] * aa_W[i*DM + d];
    X[((size_t)b * SEQ + 1) * DM + d] = acc;
}

// ---------------------------------------------------------------------------
// Weight convert+transpose: W (L,K,N) f32 -> Wt (L,N,K) bf16
// gperm=1: GEGLU column permutation for FF1 — output slot block bn (32 cols)
// sources from orig block: hi*2048 + (bn>>2)*64 + ((bn>>1)&1)*32, hi=bn&1.
// ---------------------------------------------------------------------------
__global__ __launch_bounds__(256) void wconv_k(const float* __restrict__ W,
                                               bf16* __restrict__ Wt, int K, int N,
                                               int gperm)
{
    __shared__ float t[32][33];
    int bn = blockIdx.x;
    int n0dst = bn * 32;
    int n0src;
    if (gperm) n0src = ((bn & 1) * 2048) + ((bn >> 2) * 64) + (((bn >> 1) & 1) * 32);
    else       n0src = n0dst;
    int k0 = blockIdx.y * 32;
    const float* Wl = W + (size_t)blockIdx.z * K * N;
    bf16* Wtl = Wt + (size_t)blockIdx.z * K * N;
    #pragma unroll
    for (int i = 0; i < 4; ++i) {
        int k = k0 + threadIdx.y + i*8;
        t[threadIdx.y + i*8][threadIdx.x] = Wl[(size_t)k * N + n0src + threadIdx.x];
    }
    __syncthreads();
    #pragma unroll
    for (int i = 0; i < 4; ++i) {
        int n = n0dst + threadIdx.y + i*8;
        Wtl[(size_t)n * K + k0 + threadIdx.x] = (bf16)t[threadIdx.x][threadIdx.y + i*8];
    }
}

// ---------------------------------------------------------------------------
// MFMA GEMM: C[M,N] = A[M,K](bf16 row-major) * Bt[N,K](bf16 N-major)^T
// 2-phase double-buffered LDS pipeline (prefetch tile t+1 under MFMA of t).
// geglu=1: N=4096 compute, fused a*gelu(g) epilogue writing 2048 cols.
// ---------------------------------------------------------------------------
__global__ __launch_bounds__(256) void gemm_mfma(
    const bf16* __restrict__ A, const bf16* __restrict__ Bt,
    float* __restrict__ Cf, bf16* __restrict__ Cb,
    const float* __restrict__ bias, const float* __restrict__ resid,
    int M, int N, int K, int remap, int geglu)
{
    __shared__ bf16 As[2][128*32];
    __shared__ bf16 Bs[2][128*32];
    int tid  = threadIdx.x;
    int lane = tid & 63;
    int w    = tid >> 6;
    int wm = w >> 1, wn = w & 1;
    int rowBlk = blockIdx.y * 128, colBlk = blockIdx.x * 128;
    int lm = lane & 15, lq = lane >> 4;
    int sr  = lane >> 2;
    int sc8 = (lane & 3) * 8;

    f32x4 acc[4][4];
    #pragma unroll
    for (int i = 0; i < 4; ++i)
        #pragma unroll
        for (int j = 0; j < 4; ++j) acc[i][j] = (f32x4){0.f, 0.f, 0.f, 0.f};

    int ar0 = rowBlk + w*32 + sr;      // chunk c adds 16
    int br0 = colBlk + w*32 + sr;

    // prologue: stage tile 0 into buffer 0
    #pragma unroll
    for (int c = 0; c < 2; ++c) {
        int ch = w*2 + c;
        int ar = ar0 + c*16; ar = (ar < M) ? ar : (M - 1);
        const bf16* ga = A + (size_t)ar * K + sc8;
        __builtin_amdgcn_global_load_lds(
            (const __attribute__((address_space(1))) unsigned int*)ga,
            (__attribute__((address_space(3))) unsigned int*)&As[0][ch*16*32],
            16, 0, 0);
        int br = br0 + c*16;
        const bf16* gb = Bt + (size_t)br * K + sc8;
        __builtin_amdgcn_global_load_lds(
            (const __attribute__((address_space(1))) unsigned int*)gb,
            (__attribute__((address_space(3))) unsigned int*)&Bs[0][ch*16*32],
            16, 0, 0);
    }
    __syncthreads();

    int nsteps = K >> 5;
    int cur = 0;
    for (int t = 0; t < nsteps; ++t) {
        // prefetch next tile into the other buffer
        if (t + 1 < nsteps) {
            int k0 = (t + 1) << 5;
            #pragma unroll
            for (int c = 0; c < 2; ++c) {
                int ch = w*2 + c;
                int ar = ar0 + c*16; ar = (ar < M) ? ar : (M - 1);
                const bf16* ga = A + (size_t)ar * K + k0 + sc8;
                __builtin_amdgcn_global_load_lds(
                    (const __attribute__((address_space(1))) unsigned int*)ga,
                    (__attribute__((address_space(3))) unsigned int*)&As[cur^1][ch*16*32],
                    16, 0, 0);
                int br = br0 + c*16;
                const bf16* gb = Bt + (size_t)br * K + k0 + sc8;
                __builtin_amdgcn_global_load_lds(
                    (const __attribute__((address_space(1))) unsigned int*)gb,
                    (__attribute__((address_space(3))) unsigned int*)&Bs[cur^1][ch*16*32],
                    16, 0, 0);
            }
        }
        // compute current buffer
        bf16x8 af[4], bfr[4];
        #pragma unroll
        for (int mt = 0; mt < 4; ++mt)
            af[mt] = *(const bf16x8*)&As[cur][(wm*64 + mt*16 + lm)*32 + lq*8];
        #pragma unroll
        for (int nt = 0; nt < 4; ++nt)
            bfr[nt] = *(const bf16x8*)&Bs[cur][(wn*64 + nt*16 + lm)*32 + lq*8];
        #pragma unroll
        for (int mt = 0; mt < 4; ++mt)
            #pragma unroll
            for (int nt = 0; nt < 4; ++nt)
                acc[mt][nt] = __builtin_amdgcn_mfma_f32_16x16x32_bf16(
                    af[mt], bfr[nt], acc[mt][nt], 0, 0, 0);
        __syncthreads();   // drains prefetch (vmcnt 0) + guards LDS reuse
        cur ^= 1;
    }

    if (geglu) {
        #pragma unroll
        for (int nt = 0; nt < 2; ++nt) {
            int oa = (colBlk >> 1) + wn*32 + nt*16 + lm;   // 0..2047
            float ba = bias[oa], bg = bias[oa + 2048];
            #pragma unroll
            for (int mt = 0; mt < 4; ++mt) {
                #pragma unroll
                for (int r = 0; r < 4; ++r) {
                    int gm = rowBlk + wm*64 + mt*16 + lq*4 + r;
                    if (gm < M) {
                        float a = acc[mt][nt][r] + ba;
                        float g = acc[mt][nt+2][r] + bg;
                        float gl = 0.5f * g * (1.f + erff(g * 0.70710678118654752f));
                        Cb[(size_t)gm * 2048 + oa] = (bf16)(a * gl);
                    }
                }
            }
        }
        return;
    }

    #pragma unroll
    for (int nt = 0; nt < 4; ++nt) {
        int gn = colBlk + wn*64 + nt*16 + lm;
        float bs = bias ? bias[gn] : 0.f;
        #pragma unroll
        for (int mt = 0; mt < 4; ++mt) {
            #pragma unroll
            for (int r = 0; r < 4; ++r) {
                int gm = rowBlk + wm*64 + mt*16 + lq*4 + r;
                if (gm < M) {
                    int om = remap ? ((gm/1568)*1570 + 2 + (gm % 1568)) : gm;
                    size_t off = (size_t)om * N + gn;
                    float v = acc[mt][nt][r] + bs;
                    if (resid) v += resid[off];
                    if (Cf) Cf[off] = v;
                    else    Cb[off] = (bf16)v;
                }
            }
        }
    }
}

// ---------------------------------------------------------------------------
// LayerNorm: X fp32 -> XN bf16 (wave shuffle reduce, 1 barrier)
// ---------------------------------------------------------------------------
__global__ __launch_bounds__(256) void layernorm_k(
    const float* __restrict__ X, bf16* __restrict__ XN,
    const float* __restrict__ g, const float* __restrict__ b)
{
    int row = blockIdx.x, tid = threadIdx.x;
    int wid = tid >> 6;
    const float* x = X + (size_t)row * DM;
    float v0 = x[tid], v1 = x[tid + 256];
    float s1 = v0 + v1, s2 = v0*v0 + v1*v1;
    #pragma unroll
    for (int off = 1; off < 64; off <<= 1) {
        s1 += __shfl_xor(s1, off);
        s2 += __shfl_xor(s2, off);
    }
    __shared__ float w1[4], w2[4];
    if ((tid & 63) == 0) { w1[wid] = s1; w2[wid] = s2; }
    __syncthreads();
    s1 = w1[0] + w1[1] + w1[2] + w1[3];
    s2 = w2[0] + w2[1] + w2[2] + w2[3];
    float mean = s1 * (1.f / DM);
    float var  = s2 * (1.f / DM) - mean * mean;
    float inv  = rsqrtf(var + 1e-5f);
    bf16* y = XN + (size_t)row * DM;
    y[tid]       = (bf16)((v0 - mean) * inv * g[tid]       + b[tid]);
    y[tid + 256] = (bf16)((v1 - mean) * inv * g[tid + 256] + b[tid + 256]);
}

// ---------------------------------------------------------------------------
// Special-token attention, partial pass: grid (32 bh, 13 chunks of 128 keys).
// ---------------------------------------------------------------------------
__global__ __launch_bounds__(256) void sp_part_k(
    const bf16* __restrict__ QKV, float* __restrict__ PART)
{
    __shared__ float q2[2][64];
    __shared__ float ps[2][128];
    __shared__ float red2[2][64];
    __shared__ float red[256];
    __shared__ float msh[2], dsh[2];
    int bh = blockIdx.x, ck = blockIdx.y;
    int b = bh >> 3, h = bh & 7;
    int tid = threadIdx.x;
    int k0 = ck * 128;

    if (tid < 128) {
        int qi = tid >> 6, d = tid & 63;
        q2[qi][d] = (float)QKV[((size_t)(b*SEQ + qi))*1536 + h*64 + d] * 0.125f;
    }
    __syncthreads();

    float s0 = -1e30f, s1 = -1e30f;
    int k = k0 + tid;
    if (tid < 128) {
        if (k < SEQ) {
            const bf16* kp = QKV + ((size_t)(b*SEQ + k))*1536 + 512 + h*64;
            s0 = 0.f; s1 = 0.f;
            #pragma unroll
            for (int c = 0; c < 8; ++c) {
                bf16x8 kv = *(const bf16x8*)(kp + c*8);
                #pragma unroll
                for (int e = 0; e < 8; ++e) {
                    float kf = (float)kv[e];
                    s0 += q2[0][c*8 + e] * kf;
                    s1 += q2[1][c*8 + e] * kf;
                }
            }
        }
        ps[0][tid] = s0; ps[1][tid] = s1;
    }
    __syncthreads();

    if (tid < 128) {
        int qi = tid >> 6, i = tid & 63;
        red2[qi][i] = fmaxf(ps[qi][i], ps[qi][i + 64]);
    }
    __syncthreads();
    for (int off = 32; off > 0; off >>= 1) {
        if (tid < 2*off) {
            int qi = (tid >= off) ? 1 : 0;
            int i = tid - qi*off;
            red2[qi][i] = fmaxf(red2[qi][i], red2[qi][i + off]);
        }
        __syncthreads();
    }
    if (tid < 2) msh[tid] = red2[tid][0];
    __syncthreads();
    float m0 = msh[0], m1 = msh[1];

    if (tid < 128) {
        float e0 = (k < SEQ) ? expf(s0 - m0) : 0.f;
        float e1 = (k < SEQ) ? expf(s1 - m1) : 0.f;
        ps[0][tid] = e0; ps[1][tid] = e1;
    }
    __syncthreads();
    if (tid < 128) {
        int qi = tid >> 6, i = tid & 63;
        red2[qi][i] = ps[qi][i] + ps[qi][i + 64];
    }
    __syncthreads();
    for (int off = 32; off > 0; off >>= 1) {
        if (tid < 2*off) {
            int qi = (tid >= off) ? 1 : 0;
            int i = tid - qi*off;
            red2[qi][i] += red2[qi][i + off];
        }
        __syncthreads();
    }
    if (tid < 2) dsh[tid] = red2[tid][0];
    __syncthreads();

    int d = tid & 63, kg = tid >> 6;
    float a0 = 0.f, a1 = 0.f;
    for (int kr = kg; kr < 128; kr += 4) {
        int kk = k0 + kr;
        if (kk < SEQ) {
            float vf = (float)QKV[((size_t)(b*SEQ + kk))*1536 + 1024 + h*64 + d];
            a0 += ps[0][kr] * vf;
            a1 += ps[1][kr] * vf;
        }
    }
    float* out = PART + ((size_t)(bh*2)*SPCH)*66;
    red[tid] = a0; __syncthreads();
    if (tid < 64) {
        float av = red[tid] + red[64+tid] + red[128+tid] + red[192+tid];
        out[(size_t)(0*SPCH + ck)*66 + 2 + tid] = av;
    }
    __syncthreads();
    red[tid] = a1; __syncthreads();
    if (tid < 64) {
        float av = red[tid] + red[64+tid] + red[128+tid] + red[192+tid];
        out[(size_t)(1*SPCH + ck)*66 + 2 + tid] = av;
    }
    if (tid < 2) {
        out[(size_t)(tid*SPCH + ck)*66 + 0] = msh[tid];
        out[(size_t)(tid*SPCH + ck)*66 + 1] = dsh[tid];
    }
}

// ---------------------------------------------------------------------------
// Special-token attention, reduce: grid 64 rows (bh*2+qi) x 64 threads (d).
// ---------------------------------------------------------------------------
__global__ __launch_bounds__(64) void sp_red_k(
    const float* __restrict__ PART, bf16* __restrict__ AO)
{
    int row = blockIdx.x;
    int bh = row >> 1, qi = row & 1;
    int b = bh >> 3, h = bh & 7;
    int d = threadIdx.x;
    const float* pr = PART + (size_t)row * SPCH * 66;
    float gm = -1e30f;
    #pragma unroll
    for (int c = 0; c < SPCH; ++c) gm = fmaxf(gm, pr[c*66]);
    float num = 0.f, den = 0.f;
    #pragma unroll
    for (int c = 0; c < SPCH; ++c) {
        float w = expf(pr[c*66] - gm);
        den += pr[c*66 + 1] * w;
        num += pr[c*66 + 2 + d] * w;
    }
    AO[((size_t)(b*SEQ + qi))*DM + h*64 + d] = (bf16)(num / den);
}

// ---------------------------------------------------------------------------
// In-place RoPE on q,k (bf16) for token rows >= 2
// ---------------------------------------------------------------------------
__global__ void rope_k(bf16* QKV, const float* __restrict__ sn,
                       const float* __restrict__ cs, int mode)
{
    int idx = blockIdx.x * blockDim.x + threadIdx.x;
    if (idx >= NB * NF * NT * 8 * 32) return;
    int p = idx & 31;
    int h = (idx >> 5) & 7;
    int t = (idx >> 8) % (NF * NT);
    int b = (idx >> 8) / (NF * NT);
    int ri = (mode == 0) ? (t / NT) : (t % NT);
    float c = cs[ri*64 + 2*p], s = sn[ri*64 + 2*p];
    size_t base = ((size_t)(b*SEQ + 2 + t)) * 1536 + h*64 + 2*p;
    float x0 = (float)QKV[base], x1 = (float)QKV[base + 1];
    QKV[base]     = (bf16)(x0 * c - x1 * s);
    QKV[base + 1] = (bf16)(x1 * c + x0 * s);
    base += 512;   // k
    x0 = (float)QKV[base]; x1 = (float)QKV[base + 1];
    QKV[base]     = (bf16)(x0 * c - x1 * s);
    QKV[base + 1] = (bf16)(x1 * c + x0 * s);
}

// ---------------------------------------------------------------------------
// Time attention (post-RoPE): one thread per q-row (b,h,jj,fq).
// ---------------------------------------------------------------------------
__global__ __launch_bounds__(256) void attn_time_k(
    const bf16* __restrict__ QKV, bf16* __restrict__ AO)
{
    int rid = blockIdx.x * 256 + threadIdx.x;    // 196 blocks * 256 = 50176 exact
    int fq = rid & 7;
    int x  = rid >> 3;
    int jj = x % NT;
    int bh = x / NT;
    int b = bh >> 3, h = bh & 7;
    const bf16* qp = QKV + ((size_t)(b*SEQ + 2 + fq*NT + jj))*1536 + h*64;
    bf16x8 qv[8];
    #pragma unroll
    for (int c = 0; c < 8; ++c) qv[c] = *(const bf16x8*)(qp + c*8);
    float sc[10];
    #pragma unroll
    for (int j = 0; j < 10; ++j) {
        int krow = (j < 2) ? j : (2 + (j-2)*NT + jj);
        const bf16* kp = QKV + ((size_t)(b*SEQ + krow))*1536 + 512 + h*64;
        float s = 0.f;
        #pragma unroll
        for (int c = 0; c < 8; ++c) {
            bf16x8 kv = *(const bf16x8*)(kp + c*8);
            #pragma unroll
            for (int e = 0; e < 8; ++e) s += (float)qv[c][e] * (float)kv[e];
        }
        sc[j] = s * 0.125f;
    }
    float m = sc[0];
    #pragma unroll
    for (int j = 1; j < 10; ++j) m = fmaxf(m, sc[j]);
    float sum = 0.f;
    #pragma unroll
    for (int j = 0; j < 10; ++j) { sc[j] = expf(sc[j] - m); sum += sc[j]; }
    float inv = 1.f / sum;
    float out[64];
    #pragma unroll
    for (int d = 0; d < 64; ++d) out[d] = 0.f;
    #pragma unroll
    for (int j = 0; j < 10; ++j) {
        int vrow = (j < 2) ? j : (2 + (j-2)*NT + jj);
        const bf16* vp = QKV + ((size_t)(b*SEQ + vrow))*1536 + 1024 + h*64;
        float p = sc[j] * inv;
        #pragma unroll
        for (int c = 0; c < 8; ++c) {
            bf16x8 vv = *(const bf16x8*)(vp + c*8);
            #pragma unroll
            for (int e = 0; e < 8; ++e) out[c*8 + e] += p * (float)vv[e];
        }
    }
    bf16* op = AO + ((size_t)(b*SEQ + 2 + fq*NT + jj))*DM + h*64;
    #pragma unroll
    for (int c = 0; c < 8; ++c) {
        bf16x8 ov;
        #pragma unroll
        for (int e = 0; e < 8; ++e) ov[e] = (bf16)out[c*8 + e];
        *(bf16x8*)(op + c*8) = ov;
    }
}

// ---------------------------------------------------------------------------
// Space attention (post-RoPE), MFMA flash-style.
// ---------------------------------------------------------------------------
__global__ __launch_bounds__(256) void attn_space_k(
    const bf16* __restrict__ QKV, bf16* __restrict__ AO)
{
    __shared__ __align__(16) bf16 KV[14336];      // 28KB: K blocked, then V blocked
    __shared__ __align__(16) bf16 Pb[4][3584];    // 28KB: per-wave P
    int g  = blockIdx.x;
    int qb = blockIdx.y;
    int bh = g >> 3, fi = g & 7;
    int b = bh >> 3, h = bh & 7;
    int tid = threadIdx.x;
    int w = tid >> 6, lane = tid & 63;
    int lm = lane & 15, lq = lane >> 4;

    // ---- stage K: 14 m-tiles x 2 k-chunks x 64 chunks = 1792 x 16B (7 iters)
    #pragma unroll
    for (int it = 0; it < 7; ++it) {
        int c = it*256 + tid;
        int mt  = c >> 7;
        int ks2 = (c >> 6) & 1;
        int lmc = (c >> 2) & 15;
        int lqc = c & 3;
        int key = mt*16 + lmc;
        int skey = (key < 2) ? key : ((key < 198) ? (2 + fi*NT + key - 2) : (2 + fi*NT));
        const bf16* src = QKV + ((size_t)(b*SEQ + skey))*1536 + 512 + h*64 + ks2*32 + lqc*8;
        __builtin_amdgcn_global_load_lds(
            (const __attribute__((address_space(1))) unsigned int*)src,
            (__attribute__((address_space(3))) unsigned int*)&KV[(it*256 + w*64)*8],
            16, 0, 0);
    }

    // ---- Q fragments (B-operand) straight from global
    int q0 = qb*64 + w*16;
    int qrow = q0 + lm; if (qrow > 195) qrow = 195;
    const bf16* qp = QKV + ((size_t)(b*SEQ + 2 + fi*NT + qrow))*1536 + h*64;
    bf16x8 bq0 = *(const bf16x8*)(qp + lq*8);
    bf16x8 bq1 = *(const bf16x8*)(qp + 32 + lq*8);

    __syncthreads();

    // ---- QK^T (S^T layout: row=key, col=q)
    f32x4 acc[14];
    #pragma unroll
    for (int mt = 0; mt < 14; ++mt) acc[mt] = (f32x4){0.f, 0.f, 0.f, 0.f};
    #pragma unroll
    for (int mt = 0; mt < 14; ++mt) {
        bf16x8 a0 = *(const bf16x8*)&KV[((mt*2 + 0)*64 + lm*4 + lq)*8];
        bf16x8 a1 = *(const bf16x8*)&KV[((mt*2 + 1)*64 + lm*4 + lq)*8];
        acc[mt] = __builtin_amdgcn_mfma_f32_16x16x32_bf16(a0, bq0, acc[mt], 0, 0, 0);
        acc[mt] = __builtin_amdgcn_mfma_f32_16x16x32_bf16(a1, bq1, acc[mt], 0, 0, 0);
    }

    // ---- softmax: lane q = q0+lm; keys = mt*16 + lq*4 + r
    int kbase = lq*4;
    float mx = -1e30f;
    #pragma unroll
    for (int mt = 0; mt < 14; ++mt)
        #pragma unroll
        for (int r = 0; r < 4; ++r) {
            int key = mt*16 + kbase + r;
            if (key < 198) mx = fmaxf(mx, acc[mt][r]*0.125f);
        }
    mx = fmaxf(mx, __shfl_xor(mx, 16));
    mx = fmaxf(mx, __shfl_xor(mx, 32));
    float sum = 0.f;
    #pragma unroll
    for (int mt = 0; mt < 14; ++mt)
        #pragma unroll
        for (int r = 0; r < 4; ++r) {
            int key = mt*16 + kbase + r;
            float p = (key < 198) ? expf(acc[mt][r]*0.125f - mx) : 0.f;
            acc[mt][r] = p;
            sum += p;
        }
    sum += __shfl_xor(sum, 16);
    sum += __shfl_xor(sum, 32);
    float inv = 1.f / sum;

    // ---- write P (bf16, normalized) to per-wave blocked buffer
    #pragma unroll
    for (int mt = 0; mt < 14; ++mt) {
        int K0 = mt*16 + kbase;
        int chunk = (K0 >> 5)*64 + lm*4 + ((K0 >> 3) & 3);
        bf16x4 pv;
        #pragma unroll
        for (int r = 0; r < 4; ++r) pv[r] = (bf16)(acc[mt][r] * inv);
        *(bf16x4*)&Pb[w][chunk*8 + (K0 & 7)] = pv;
    }
    __syncthreads();   // all waves done reading K from KV

    // ---- stage V into KV (blocked V^T-consumable layout), zero s>=198
    {
        int dchunk = tid >> 5, rr = tid & 31;
        #pragma unroll
        for (int si = 0; si < 7; ++si) {
            int s = si*32 + rr;
            bf16x8 vv;
            if (s < 198) {
                int sk = (s < 2) ? s : (2 + fi*NT + s - 2);
                vv = *(const bf16x8*)(QKV + ((size_t)(b*SEQ + sk))*1536 + 1024 + h*64 + dchunk*8);
            } else {
                #pragma unroll
                for (int e = 0; e < 8; ++e) vv[e] = (bf16)0.f;
            }
            int slot = rr >> 3, j2 = s & 7;
            #pragma unroll
            for (int j = 0; j < 8; ++j) {
                int d = dchunk*8 + j;
                KV[(((si*4 + (d >> 4))*16 + (d & 15))*4 + slot)*8 + j2] = vv[j];
            }
        }
    }
    __syncthreads();

    // ---- AV: O[q][d] = P x V^T
    f32x4 acc2[4];
    #pragma unroll
    for (int nt = 0; nt < 4; ++nt) acc2[nt] = (f32x4){0.f, 0.f, 0.f, 0.f};
    #pragma unroll
    for (int ks = 0; ks < 7; ++ks) {
        bf16x8 pa = *(const bf16x8*)&Pb[w][(ks*64 + lm*4 + lq)*8];
        #pragma unroll
        for (int nt = 0; nt < 4; ++nt) {
            bf16x8 bv = *(const bf16x8*)&KV[((((ks*4 + nt)*16 + lm)*4 + lq)*8)];
            acc2[nt] = __builtin_amdgcn_mfma_f32_16x16x32_bf16(pa, bv, acc2[nt], 0, 0, 0);
        }
    }

    // ---- store
    #pragma unroll
    for (int nt = 0; nt < 4; ++nt) {
        int d = nt*16 + lm;
        #pragma unroll
        for (int r = 0; r < 4; ++r) {
            int q = q0 + lq*4 + r;
            if (q < 196)
                AO[((size_t)(b*SEQ + 2 + fi*NT + q))*DM + h*64 + d] = (bf16)acc2[nt][r];
        }
    }
}

// ---------------------------------------------------------------------------
// Final head: LN(x[:,0]) @ out_W (512,2) + out_b -> f32 out (4,2)
// ---------------------------------------------------------------------------
__global__ __launch_bounds__(256) void final_head_k(
    const float* __restrict__ X, const float* __restrict__ g, const float* __restrict__ bt,
    const float* __restrict__ W, const float* __restrict__ bo, float* __restrict__ out)
{
    int b = blockIdx.x, tid = threadIdx.x;
    const float* x = X + (size_t)b * SEQ * DM;
    float v0 = x[tid], v1 = x[tid + 256];
    __shared__ float r1[256], r2[256];
    r1[tid] = v0 + v1;
    r2[tid] = v0*v0 + v1*v1;
    __syncthreads();
    for (int off = 128; off > 0; off >>= 1) {
        if (tid < off) { r1[tid] += r1[tid+off]; r2[tid] += r2[tid+off]; }
        __syncthreads();
    }
    float mean = r1[0] * (1.f / DM);
    float var  = r2[0] * (1.f / DM) - mean * mean;
    float inv  = rsqrtf(var + 1e-5f);
    float xn0 = (v0 - mean) * inv * g[tid]       + bt[tid];
    float xn1 = (v1 - mean) * inv * g[tid + 256] + bt[tid + 256];
    __syncthreads();
    r1[tid] = xn0 * W[tid*2]     + xn1 * W[(tid+256)*2];
    r2[tid] = xn0 * W[tid*2 + 1] + xn1 * W[(tid+256)*2 + 1];
    __syncthreads();
    for (int off = 128; off > 0; off >>= 1) {
        if (tid < off) { r1[tid] += r1[tid+off]; r2[tid] += r2[tid+off]; }
        __syncthreads();
    }
    if (tid == 0) {
        out[b*2 + 0] = r1[0] + bo[0];
        out[b*2 + 1] = r2[0] + bo[1];
    }
}

// ---------------------------------------------------------------------------
extern "C" void kernel_launch(void* const* d_in, const int* in_sizes, int n_in,
                              void* d_out, int out_size, void* d_ws, size_t ws_size,
                              hipStream_t stream)
{
    const float* video    = (const float*)d_in[0];
    const float* aa_w     = (const float*)d_in[1];
    const float* patch_W  = (const float*)d_in[2];
    const float* patch_b  = (const float*)d_in[3];
    const float* cls_tok  = (const float*)d_in[4];
    const float* aa_W     = (const float*)d_in[5];
    const float* aa_b     = (const float*)d_in[6];
    const float* ln_t_g   = (const float*)d_in[7];
    const float* ln_t_b   = (const float*)d_in[8];
    const float* t_qkv    = (const float*)d_in[9];
    const float* t_outW   = (const float*)d_in[10];
    const float* t_outb   = (const float*)d_in[11];
    const float* ln_s_g   = (const float*)d_in[12];
    const float* ln_s_b   = (const float*)d_in[13];
    const float* s_qkv    = (const float*)d_in[14];
    const float* s_outW   = (const float*)d_in[15];
    const float* s_outb   = (const float*)d_in[16];
    const float* ln_f_g   = (const float*)d_in[17];
    const float* ln_f_b   = (const float*)d_in[18];
    const float* ff_W1    = (const float*)d_in[19];
    const float* ff_b1    = (const float*)d_in[20];
    const float* ff_W2    = (const float*)d_in[21];
    const float* ff_b2    = (const float*)d_in[22];
    const float* out_ln_g = (const float*)d_in[23];
    const float* out_ln_b = (const float*)d_in[24];
    const float* out_W    = (const float*)d_in[25];
    const float* out_b    = (const float*)d_in[26];

    // ---- workspace layout ----
    char* p = (char*)d_ws;
    auto alloc = [&](size_t bytes) { char* r = p; p += (bytes + 255) & ~(size_t)255; return r; };
    float* X   = (float*)alloc((size_t)MR * DM * 4);
    bf16*  XN  = (bf16*)alloc((size_t)MR * DM * 2);
    bf16*  R   = (bf16*)alloc((size_t)MR * 4096 * 2);
    bf16*  B2  = (bf16*)alloc((size_t)MR * 2048 * 2);
    bf16*  Wt  = (bf16*)alloc((size_t)63307776 * 2);
    float* PART= (float*)alloc((size_t)64 * SPCH * 66 * 4);
    float* fsin = (float*)alloc(8*64*4);
    float* fcos = (float*)alloc(8*64*4);
    float* isin = (float*)alloc(196*64*4);
    float* icos = (float*)alloc(196*64*4);

    bf16* QKV = R;
    bf16* VP  = R;
    bf16* AO  = XN;

    bf16* patchW_t = Wt;
    bf16* tqkv_t   = patchW_t + 393216;
    bf16* toutW_t  = tqkv_t   + 9437184;
    bf16* sqkv_t   = toutW_t  + 3145728;
    bf16* soutW_t  = sqkv_t   + 9437184;
    bf16* ffW1_t   = soutW_t  + 3145728;
    bf16* ffW2_t   = ffW1_t   + 25165824;

    // ---- weight conversion ----
    dim3 wb(32, 8);
    wconv_k<<<dim3(1536/32, 512/32, 12), wb, 0, stream>>>(t_qkv,  tqkv_t,  512, 1536, 0);
    wconv_k<<<dim3( 512/32, 512/32, 12), wb, 0, stream>>>(t_outW, toutW_t, 512,  512, 0);
    wconv_k<<<dim3(1536/32, 512/32, 12), wb, 0, stream>>>(s_qkv,  sqkv_t,  512, 1536, 0);
    wconv_k<<<dim3( 512/32, 512/32, 12), wb, 0, stream>>>(s_outW, soutW_t, 512,  512, 0);
    wconv_k<<<dim3(4096/32, 512/32, 12), wb, 0, stream>>>(ff_W1,  ffW1_t,  512, 4096, 1);
    wconv_k<<<dim3( 512/32,2048/32, 12), wb, 0, stream>>>(ff_W2,  ffW2_t, 2048,  512, 0);
    wconv_k<<<dim3( 512/32, 768/32,  1), wb, 0, stream>>>(patch_W, patchW_t, 768, 512, 0);

    build_rot_k<<<25, 256, 0, stream>>>(fsin, fcos, isin, icos);

    // ---- patchify + token embedding ----
    patch_gather_k<<<(NB*NF*NT*768 + 255)/256, 256, 0, stream>>>(video, VP);
    init_special_k<<<(NB*DM + 255)/256, 256, 0, stream>>>(X, cls_tok, aa_w, aa_W, aa_b);
    gemm_mfma<<<dim3(512/128, 6272/128), 256, 0, stream>>>(
        VP, patchW_t, X, nullptr, patch_b, nullptr, 6272, 512, 768, 1, 0);

    for (int l = 0; l < 12; ++l) {
        // ---- time attention ----
        layernorm_k<<<MR, 256, 0, stream>>>(X, XN, ln_t_g + l*DM, ln_t_b + l*DM);
        gemm_mfma<<<dim3(12, 50), 256, 0, stream>>>(
            XN, tqkv_t + (size_t)l*786432, nullptr, QKV, nullptr, nullptr, MR, 1536, 512, 0, 0);
        sp_part_k<<<dim3(32, SPCH), 256, 0, stream>>>(QKV, PART);
        sp_red_k<<<64, 64, 0, stream>>>(PART, AO);
        rope_k<<<6272, 256, 0, stream>>>(QKV, fsin, fcos, 0);
        attn_time_k<<<196, 256, 0, stream>>>(QKV, AO);
        gemm_mfma<<<dim3(4, 50), 256, 0, stream>>>(
            AO, toutW_t + (size_t)l*262144, X, nullptr, t_outb + l*DM, X, MR, 512, 512, 0, 0);

        // ---- space attention ----
        layernorm_k<<<MR, 256, 0, stream>>>(X, XN, ln_s_g + l*DM, ln_s_b + l*DM);
        gemm_mfma<<<dim3(12, 50), 256, 0, stream>>>(
            XN, sqkv_t + (size_t)l*786432, nullptr, QKV, nullptr, nullptr, MR, 1536, 512, 0, 0);
        sp_part_k<<<dim3(32, SPCH), 256, 0, stream>>>(QKV, PART);
        sp_red_k<<<64, 64, 0, stream>>>(PART, AO);
        rope_k<<<6272, 256, 0, stream>>>(QKV, isin, icos, 1);
        attn_space_k<<<dim3(256, 4), 256, 0, stream>>>(QKV, AO);
        gemm_mfma<<<dim3(4, 50), 256, 0, stream>>>(
            AO, soutW_t + (size_t)l*262144, X, nullptr, s_outb + l*DM, X, MR, 512, 512, 0, 0);

        // ---- GEGLU FF (gelu fused into FF1 epilogue via permuted W1) ----
        layernorm_k<<<MR, 256, 0, stream>>>(X, XN, ln_f_g + l*DM, ln_f_b + l*DM);
        gemm_mfma<<<dim3(32, 50), 256, 0, stream>>>(
            XN, ffW1_t + (size_t)l*2097152, nullptr, B2, ff_b1 + (size_t)l*4096, nullptr, MR, 4096, 512, 0, 1);
        gemm_mfma<<<dim3(4, 50), 256, 0, stream>>>(
            B2, ffW2_t + (size_t)l*1048576, X, nullptr, ff_b2 + l*DM, X, MR, 512, 2048, 0, 0);
    }

    final_head_k<<<NB, 256, 0, stream>>>(X, out_ln_g, out_ln_b, out_W, out_b, (float*)d_out);
}

// Round 4
// 4911.018 us; speedup vs baseline: 1.0759x; 1.0759x over previous
//
#include <hip/hip_runtime.h>
#include <math.h>

typedef __bf16 bf16;
typedef __bf16 bf16x8 __attribute__((ext_vector_type(8)));
typedef __bf16 bf16x4 __attribute__((ext_vector_type(4)));
typedef float  f32x4  __attribute__((ext_vector_type(4)));

#define SEQ   1570
#define NB    4
#define NF    8
#define NT    196
#define DM    512
#define MR    (NB*SEQ)   // 6280 rows
#define SPCH  13         // special-attn key chunks of 128

// ---------------------------------------------------------------------------
// Rotary tables
// ---------------------------------------------------------------------------
__global__ void build_rot_k(float* fsin, float* fcos, float* isin, float* icos)
{
    int tid = blockIdx.x * blockDim.x + threadIdx.x;
    if (tid < NF * 32) {
        int fi = tid >> 5, i = tid & 31;
        float inv = powf(10000.f, -(2.f * i) / 64.f);
        float v = fi * inv;
        float s = sinf(v), c = cosf(v);
        fsin[fi*64 + 2*i] = s; fsin[fi*64 + 2*i + 1] = s;
        fcos[fi*64 + 2*i] = c; fcos[fi*64 + 2*i + 1] = c;
    }
    if (tid < NT * 32) {
        int t = tid >> 5, i = tid & 31;
        int hi = t / 14, wi = t % 14;
        const float PI = 3.14159265358979323846f;
        float v;
        if (i < 16) {
            float scale = 1.f + 4.f * i / 15.f;
            v = (-1.f + 2.f * hi / 13.f) * scale * PI;
        } else {
            float scale = 1.f + 4.f * (i - 16) / 15.f;
            v = (-1.f + 2.f * wi / 13.f) * scale * PI;
        }
        float s = sinf(v), c = cosf(v);
        isin[t*64 + 2*i] = s; isin[t*64 + 2*i + 1] = s;
        icos[t*64 + 2*i] = c; icos[t*64 + 2*i + 1] = c;
    }
}

// ---------------------------------------------------------------------------
// Patchify: video (4,8,3,224,224) f32 -> VP (6272,768) bf16
// ---------------------------------------------------------------------------
__global__ void patch_gather_k(const float* __restrict__ video, bf16* __restrict__ VP)
{
    int idx = blockIdx.x * blockDim.x + threadIdx.x;
    if (idx >= NB * NF * NT * 768) return;
    int kk  = idx % 768;
    int row = (idx / 768) % (NF * NT);
    int b   = idx / (768 * NF * NT);
    int ch = kk % 3, pp = kk / 3;
    int pr = pp >> 4, pc = pp & 15;
    int fi = row / NT, t = row % NT;
    int hi = t / 14, wi = t % 14;
    size_t src = ((((size_t)b * NF + fi) * 3 + ch) * 224 + (hi*16 + pr)) * 224 + (wi*16 + pc);
    VP[idx] = (bf16)video[src];
}

// ---------------------------------------------------------------------------
// cls token + action-angle rows (fp32 X)
// ---------------------------------------------------------------------------
__global__ void init_special_k(float* X, const float* __restrict__ cls,
                               const float* __restrict__ aa_w,
                               const float* __restrict__ aa_W,
                               const float* __restrict__ aa_b)
{
    int idx = blockIdx.x * blockDim.x + threadIdx.x;
    if (idx >= NB * DM) return;
    int b = idx >> 9, d = idx & 511;
    X[(size_t)b * SEQ * DM + d] = cls[d];
    float acc = aa_b[d];
    for (int i = 0; i < 18; ++i) acc += aa_w[b*18 + i] * aa_W[i*DM + d];
    X[((size_t)b * SEQ + 1) * DM + d] = acc;
}

// ---------------------------------------------------------------------------
// Weight convert+transpose: W (L,K,N) f32 -> Wt (L,N,K) bf16
// gperm=1: GEGLU column permutation for FF1.
// ---------------------------------------------------------------------------
__global__ __launch_bounds__(256) void wconv_k(const float* __restrict__ W,
                                               bf16* __restrict__ Wt, int K, int N,
                                               int gperm)
{
    __shared__ float t[32][33];
    int bn = blockIdx.x;
    int n0dst = bn * 32;
    int n0src;
    if (gperm) n0src = ((bn & 1) * 2048) + ((bn >> 2) * 64) + (((bn >> 1) & 1) * 32);
    else       n0src = n0dst;
    int k0 = blockIdx.y * 32;
    const float* Wl = W + (size_t)blockIdx.z * K * N;
    bf16* Wtl = Wt + (size_t)blockIdx.z * K * N;
    #pragma unroll
    for (int i = 0; i < 4; ++i) {
        int k = k0 + threadIdx.y + i*8;
        t[threadIdx.y + i*8][threadIdx.x] = Wl[(size_t)k * N + n0src + threadIdx.x];
    }
    __syncthreads();
    #pragma unroll
    for (int i = 0; i < 4; ++i) {
        int n = n0dst + threadIdx.y + i*8;
        Wtl[(size_t)n * K + k0 + threadIdx.x] = (bf16)t[threadIdx.x][threadIdx.y + i*8];
    }
}

// ---------------------------------------------------------------------------
// MFMA GEMM: C[M,N] = A[M,K](bf16 row-major) * Bt[N,K](bf16 N-major)^T
// 128x128 tile, BK=32, single-buffered (16KB LDS -> high occupancy).
// geglu=1: N=4096 compute, fused a*gelu(g) epilogue writing 2048 cols.
// ---------------------------------------------------------------------------
__global__ __launch_bounds__(256) void gemm_mfma(
    const bf16* __restrict__ A, const bf16* __restrict__ Bt,
    float* __restrict__ Cf, bf16* __restrict__ Cb,
    const float* __restrict__ bias, const float* __restrict__ resid,
    int M, int N, int K, int remap, int geglu)
{
    __shared__ bf16 As[128*32];
    __shared__ bf16 Bs[128*32];
    int tid  = threadIdx.x;
    int lane = tid & 63;
    int w    = tid >> 6;
    int wm = w >> 1, wn = w & 1;
    int rowBlk = blockIdx.y * 128, colBlk = blockIdx.x * 128;
    int lm = lane & 15, lq = lane >> 4;
    int sr  = lane >> 2;
    int sc8 = (lane & 3) * 8;

    f32x4 acc[4][4];
    #pragma unroll
    for (int i = 0; i < 4; ++i)
        #pragma unroll
        for (int j = 0; j < 4; ++j) acc[i][j] = (f32x4){0.f, 0.f, 0.f, 0.f};

    for (int k0 = 0; k0 < K; k0 += 32) {
        #pragma unroll
        for (int c = 0; c < 2; ++c) {
            int ch = w*2 + c;
            int ar = rowBlk + ch*16 + sr;
            ar = (ar < M) ? ar : (M - 1);
            const bf16* ga = A + (size_t)ar * K + k0 + sc8;
            __builtin_amdgcn_global_load_lds(
                (const __attribute__((address_space(1))) unsigned int*)ga,
                (__attribute__((address_space(3))) unsigned int*)&As[ch*16*32],
                16, 0, 0);
            int br = colBlk + ch*16 + sr;
            const bf16* gb = Bt + (size_t)br * K + k0 + sc8;
            __builtin_amdgcn_global_load_lds(
                (const __attribute__((address_space(1))) unsigned int*)gb,
                (__attribute__((address_space(3))) unsigned int*)&Bs[ch*16*32],
                16, 0, 0);
        }
        __syncthreads();
        bf16x8 af[4], bfr[4];
        #pragma unroll
        for (int mt = 0; mt < 4; ++mt)
            af[mt] = *(const bf16x8*)&As[(wm*64 + mt*16 + lm)*32 + lq*8];
        #pragma unroll
        for (int nt = 0; nt < 4; ++nt)
            bfr[nt] = *(const bf16x8*)&Bs[(wn*64 + nt*16 + lm)*32 + lq*8];
        #pragma unroll
        for (int mt = 0; mt < 4; ++mt)
            #pragma unroll
            for (int nt = 0; nt < 4; ++nt)
                acc[mt][nt] = __builtin_amdgcn_mfma_f32_16x16x32_bf16(
                    af[mt], bfr[nt], acc[mt][nt], 0, 0, 0);
        __syncthreads();
    }

    if (geglu) {
        #pragma unroll
        for (int nt = 0; nt < 2; ++nt) {
            int oa = (colBlk >> 1) + wn*32 + nt*16 + lm;   // 0..2047
            float ba = bias[oa], bg = bias[oa + 2048];
            #pragma unroll
            for (int mt = 0; mt < 4; ++mt) {
                #pragma unroll
                for (int r = 0; r < 4; ++r) {
                    int gm = rowBlk + wm*64 + mt*16 + lq*4 + r;
                    if (gm < M) {
                        float a = acc[mt][nt][r] + ba;
                        float g = acc[mt][nt+2][r] + bg;
                        float gl = 0.5f * g * (1.f + erff(g * 0.70710678118654752f));
                        Cb[(size_t)gm * 2048 + oa] = (bf16)(a * gl);
                    }
                }
            }
        }
        return;
    }

    #pragma unroll
    for (int nt = 0; nt < 4; ++nt) {
        int gn = colBlk + wn*64 + nt*16 + lm;
        float bs = bias ? bias[gn] : 0.f;
        #pragma unroll
        for (int mt = 0; mt < 4; ++mt) {
            #pragma unroll
            for (int r = 0; r < 4; ++r) {
                int gm = rowBlk + wm*64 + mt*16 + lq*4 + r;
                if (gm < M) {
                    int om = remap ? ((gm/1568)*1570 + 2 + (gm % 1568)) : gm;
                    size_t off = (size_t)om * N + gn;
                    float v = acc[mt][nt][r] + bs;
                    if (resid) v += resid[off];
                    if (Cf) Cf[off] = v;
                    else    Cb[off] = (bf16)v;
                }
            }
        }
    }
}

// ---------------------------------------------------------------------------
// M64 variant: 64x128 tile, BK=32, 12KB LDS. For small-N / small-M GEMMs
// (out-proj, FF2, patch) where the 128x128 grid leaves CUs idle.
// Each wave computes 32x64 (acc[2][4]).
// ---------------------------------------------------------------------------
__global__ __launch_bounds__(256) void gemm_mfma64(
    const bf16* __restrict__ A, const bf16* __restrict__ Bt,
    float* __restrict__ Cf, bf16* __restrict__ Cb,
    const float* __restrict__ bias, const float* __restrict__ resid,
    int M, int N, int K, int remap)
{
    __shared__ bf16 As[64*32];
    __shared__ bf16 Bs[128*32];
    int tid  = threadIdx.x;
    int lane = tid & 63;
    int w    = tid >> 6;
    int wm = w >> 1, wn = w & 1;
    int rowBlk = blockIdx.y * 64, colBlk = blockIdx.x * 128;
    int lm = lane & 15, lq = lane >> 4;
    int sr  = lane >> 2;
    int sc8 = (lane & 3) * 8;

    f32x4 acc[2][4];
    #pragma unroll
    for (int i = 0; i < 2; ++i)
        #pragma unroll
        for (int j = 0; j < 4; ++j) acc[i][j] = (f32x4){0.f, 0.f, 0.f, 0.f};

    for (int k0 = 0; k0 < K; k0 += 32) {
        // A: wave w stages rows w*16 .. w*16+15
        {
            int ar = rowBlk + w*16 + sr;
            ar = (ar < M) ? ar : (M - 1);
            const bf16* ga = A + (size_t)ar * K + k0 + sc8;
            __builtin_amdgcn_global_load_lds(
                (const __attribute__((address_space(1))) unsigned int*)ga,
                (__attribute__((address_space(3))) unsigned int*)&As[w*16*32],
                16, 0, 0);
        }
        #pragma unroll
        for (int c = 0; c < 2; ++c) {
            int ch = w*2 + c;
            int br = colBlk + ch*16 + sr;
            const bf16* gb = Bt + (size_t)br * K + k0 + sc8;
            __builtin_amdgcn_global_load_lds(
                (const __attribute__((address_space(1))) unsigned int*)gb,
                (__attribute__((address_space(3))) unsigned int*)&Bs[ch*16*32],
                16, 0, 0);
        }
        __syncthreads();
        bf16x8 af[2], bfr[4];
        #pragma unroll
        for (int mt = 0; mt < 2; ++mt)
            af[mt] = *(const bf16x8*)&As[(wm*32 + mt*16 + lm)*32 + lq*8];
        #pragma unroll
        for (int nt = 0; nt < 4; ++nt)
            bfr[nt] = *(const bf16x8*)&Bs[(wn*64 + nt*16 + lm)*32 + lq*8];
        #pragma unroll
        for (int mt = 0; mt < 2; ++mt)
            #pragma unroll
            for (int nt = 0; nt < 4; ++nt)
                acc[mt][nt] = __builtin_amdgcn_mfma_f32_16x16x32_bf16(
                    af[mt], bfr[nt], acc[mt][nt], 0, 0, 0);
        __syncthreads();
    }

    #pragma unroll
    for (int nt = 0; nt < 4; ++nt) {
        int gn = colBlk + wn*64 + nt*16 + lm;
        float bs = bias ? bias[gn] : 0.f;
        #pragma unroll
        for (int mt = 0; mt < 2; ++mt) {
            #pragma unroll
            for (int r = 0; r < 4; ++r) {
                int gm = rowBlk + wm*32 + mt*16 + lq*4 + r;
                if (gm < M) {
                    int om = remap ? ((gm/1568)*1570 + 2 + (gm % 1568)) : gm;
                    size_t off = (size_t)om * N + gn;
                    float v = acc[mt][nt][r] + bs;
                    if (resid) v += resid[off];
                    if (Cf) Cf[off] = v;
                    else    Cb[off] = (bf16)v;
                }
            }
        }
    }
}

// ---------------------------------------------------------------------------
// LayerNorm: X fp32 -> XN bf16 (wave shuffle reduce, 1 barrier)
// ---------------------------------------------------------------------------
__global__ __launch_bounds__(256) void layernorm_k(
    const float* __restrict__ X, bf16* __restrict__ XN,
    const float* __restrict__ g, const float* __restrict__ b)
{
    int row = blockIdx.x, tid = threadIdx.x;
    int wid = tid >> 6;
    const float* x = X + (size_t)row * DM;
    float v0 = x[tid], v1 = x[tid + 256];
    float s1 = v0 + v1, s2 = v0*v0 + v1*v1;
    #pragma unroll
    for (int off = 1; off < 64; off <<= 1) {
        s1 += __shfl_xor(s1, off);
        s2 += __shfl_xor(s2, off);
    }
    __shared__ float w1[4], w2[4];
    if ((tid & 63) == 0) { w1[wid] = s1; w2[wid] = s2; }
    __syncthreads();
    s1 = w1[0] + w1[1] + w1[2] + w1[3];
    s2 = w2[0] + w2[1] + w2[2] + w2[3];
    float mean = s1 * (1.f / DM);
    float var  = s2 * (1.f / DM) - mean * mean;
    float inv  = rsqrtf(var + 1e-5f);
    bf16* y = XN + (size_t)row * DM;
    y[tid]       = (bf16)((v0 - mean) * inv * g[tid]       + b[tid]);
    y[tid + 256] = (bf16)((v1 - mean) * inv * g[tid + 256] + b[tid + 256]);
}

// ---------------------------------------------------------------------------
// Special-token attention, partial pass: grid (32 bh, 13 chunks of 128 keys).
// ---------------------------------------------------------------------------
__global__ __launch_bounds__(256) void sp_part_k(
    const bf16* __restrict__ QKV, float* __restrict__ PART)
{
    __shared__ float q2[2][64];
    __shared__ float ps[2][128];
    __shared__ float red2[2][64];
    __shared__ float red[256];
    __shared__ float msh[2], dsh[2];
    int bh = blockIdx.x, ck = blockIdx.y;
    int b = bh >> 3, h = bh & 7;
    int tid = threadIdx.x;
    int k0 = ck * 128;

    if (tid < 128) {
        int qi = tid >> 6, d = tid & 63;
        q2[qi][d] = (float)QKV[((size_t)(b*SEQ + qi))*1536 + h*64 + d] * 0.125f;
    }
    __syncthreads();

    float s0 = -1e30f, s1 = -1e30f;
    int k = k0 + tid;
    if (tid < 128) {
        if (k < SEQ) {
            const bf16* kp = QKV + ((size_t)(b*SEQ + k))*1536 + 512 + h*64;
            s0 = 0.f; s1 = 0.f;
            #pragma unroll
            for (int c = 0; c < 8; ++c) {
                bf16x8 kv = *(const bf16x8*)(kp + c*8);
                #pragma unroll
                for (int e = 0; e < 8; ++e) {
                    float kf = (float)kv[e];
                    s0 += q2[0][c*8 + e] * kf;
                    s1 += q2[1][c*8 + e] * kf;
                }
            }
        }
        ps[0][tid] = s0; ps[1][tid] = s1;
    }
    __syncthreads();

    if (tid < 128) {
        int qi = tid >> 6, i = tid & 63;
        red2[qi][i] = fmaxf(ps[qi][i], ps[qi][i + 64]);
    }
    __syncthreads();
    for (int off = 32; off > 0; off >>= 1) {
        if (tid < 2*off) {
            int qi = (tid >= off) ? 1 : 0;
            int i = tid - qi*off;
            red2[qi][i] = fmaxf(red2[qi][i], red2[qi][i + off]);
        }
        __syncthreads();
    }
    if (tid < 2) msh[tid] = red2[tid][0];
    __syncthreads();
    float m0 = msh[0], m1 = msh[1];

    if (tid < 128) {
        float e0 = (k < SEQ) ? expf(s0 - m0) : 0.f;
        float e1 = (k < SEQ) ? expf(s1 - m1) : 0.f;
        ps[0][tid] = e0; ps[1][tid] = e1;
    }
    __syncthreads();
    if (tid < 128) {
        int qi = tid >> 6, i = tid & 63;
        red2[qi][i] = ps[qi][i] + ps[qi][i + 64];
    }
    __syncthreads();
    for (int off = 32; off > 0; off >>= 1) {
        if (tid < 2*off) {
            int qi = (tid >= off) ? 1 : 0;
            int i = tid - qi*off;
            red2[qi][i] += red2[qi][i + off];
        }
        __syncthreads();
    }
    if (tid < 2) dsh[tid] = red2[tid][0];
    __syncthreads();

    int d = tid & 63, kg = tid >> 6;
    float a0 = 0.f, a1 = 0.f;
    for (int kr = kg; kr < 128; kr += 4) {
        int kk = k0 + kr;
        if (kk < SEQ) {
            float vf = (float)QKV[((size_t)(b*SEQ + kk))*1536 + 1024 + h*64 + d];
            a0 += ps[0][kr] * vf;
            a1 += ps[1][kr] * vf;
        }
    }
    float* out = PART + ((size_t)(bh*2)*SPCH)*66;
    red[tid] = a0; __syncthreads();
    if (tid < 64) {
        float av = red[tid] + red[64+tid] + red[128+tid] + red[192+tid];
        out[(size_t)(0*SPCH + ck)*66 + 2 + tid] = av;
    }
    __syncthreads();
    red[tid] = a1; __syncthreads();
    if (tid < 64) {
        float av = red[tid] + red[64+tid] + red[128+tid] + red[192+tid];
        out[(size_t)(1*SPCH + ck)*66 + 2 + tid] = av;
    }
    if (tid < 2) {
        out[(size_t)(tid*SPCH + ck)*66 + 0] = msh[tid];
        out[(size_t)(tid*SPCH + ck)*66 + 1] = dsh[tid];
    }
}

// ---------------------------------------------------------------------------
// Special-token attention, reduce: grid 64 rows (bh*2+qi) x 64 threads (d).
// ---------------------------------------------------------------------------
__global__ __launch_bounds__(64) void sp_red_k(
    const float* __restrict__ PART, bf16* __restrict__ AO)
{
    int row = blockIdx.x;
    int bh = row >> 1, qi = row & 1;
    int b = bh >> 3, h = bh & 7;
    int d = threadIdx.x;
    const float* pr = PART + (size_t)row * SPCH * 66;
    float gm = -1e30f;
    #pragma unroll
    for (int c = 0; c < SPCH; ++c) gm = fmaxf(gm, pr[c*66]);
    float num = 0.f, den = 0.f;
    #pragma unroll
    for (int c = 0; c < SPCH; ++c) {
        float w = expf(pr[c*66] - gm);
        den += pr[c*66 + 1] * w;
        num += pr[c*66 + 2 + d] * w;
    }
    AO[((size_t)(b*SEQ + qi))*DM + h*64 + d] = (bf16)(num / den);
}

// ---------------------------------------------------------------------------
// In-place RoPE on q,k (bf16) for token rows >= 2
// ---------------------------------------------------------------------------
__global__ void rope_k(bf16* QKV, const float* __restrict__ sn,
                       const float* __restrict__ cs, int mode)
{
    int idx = blockIdx.x * blockDim.x + threadIdx.x;
    if (idx >= NB * NF * NT * 8 * 32) return;
    int p = idx & 31;
    int h = (idx >> 5) & 7;
    int t = (idx >> 8) % (NF * NT);
    int b = (idx >> 8) / (NF * NT);
    int ri = (mode == 0) ? (t / NT) : (t % NT);
    float c = cs[ri*64 + 2*p], s = sn[ri*64 + 2*p];
    size_t base = ((size_t)(b*SEQ + 2 + t)) * 1536 + h*64 + 2*p;
    float x0 = (float)QKV[base], x1 = (float)QKV[base + 1];
    QKV[base]     = (bf16)(x0 * c - x1 * s);
    QKV[base + 1] = (bf16)(x1 * c + x0 * s);
    base += 512;   // k
    x0 = (float)QKV[base]; x1 = (float)QKV[base + 1];
    QKV[base]     = (bf16)(x0 * c - x1 * s);
    QKV[base + 1] = (bf16)(x1 * c + x0 * s);
}

// ---------------------------------------------------------------------------
// Time attention (post-RoPE): one thread per q-row (b,h,jj,fq).
// ---------------------------------------------------------------------------
__global__ __launch_bounds__(256) void attn_time_k(
    const bf16* __restrict__ QKV, bf16* __restrict__ AO)
{
    int rid = blockIdx.x * 256 + threadIdx.x;    // 196 blocks * 256 = 50176 exact
    int fq = rid & 7;
    int x  = rid >> 3;
    int jj = x % NT;
    int bh = x / NT;
    int b = bh >> 3, h = bh & 7;
    const bf16* qp = QKV + ((size_t)(b*SEQ + 2 + fq*NT + jj))*1536 + h*64;
    bf16x8 qv[8];
    #pragma unroll
    for (int c = 0; c < 8; ++c) qv[c] = *(const bf16x8*)(qp + c*8);
    float sc[10];
    #pragma unroll
    for (int j = 0; j < 10; ++j) {
        int krow = (j < 2) ? j : (2 + (j-2)*NT + jj);
        const bf16* kp = QKV + ((size_t)(b*SEQ + krow))*1536 + 512 + h*64;
        float s = 0.f;
        #pragma unroll
        for (int c = 0; c < 8; ++c) {
            bf16x8 kv = *(const bf16x8*)(kp + c*8);
            #pragma unroll
            for (int e = 0; e < 8; ++e) s += (float)qv[c][e] * (float)kv[e];
        }
        sc[j] = s * 0.125f;
    }
    float m = sc[0];
    #pragma unroll
    for (int j = 1; j < 10; ++j) m = fmaxf(m, sc[j]);
    float sum = 0.f;
    #pragma unroll
    for (int j = 0; j < 10; ++j) { sc[j] = expf(sc[j] - m); sum += sc[j]; }
    float inv = 1.f / sum;
    float out[64];
    #pragma unroll
    for (int d = 0; d < 64; ++d) out[d] = 0.f;
    #pragma unroll
    for (int j = 0; j < 10; ++j) {
        int vrow = (j < 2) ? j : (2 + (j-2)*NT + jj);
        const bf16* vp = QKV + ((size_t)(b*SEQ + vrow))*1536 + 1024 + h*64;
        float p = sc[j] * inv;
        #pragma unroll
        for (int c = 0; c < 8; ++c) {
            bf16x8 vv = *(const bf16x8*)(vp + c*8);
            #pragma unroll
            for (int e = 0; e < 8; ++e) out[c*8 + e] += p * (float)vv[e];
        }
    }
    bf16* op = AO + ((size_t)(b*SEQ + 2 + fq*NT + jj))*DM + h*64;
    #pragma unroll
    for (int c = 0; c < 8; ++c) {
        bf16x8 ov;
        #pragma unroll
        for (int e = 0; e < 8; ++e) ov[e] = (bf16)out[c*8 + e];
        *(bf16x8*)(op + c*8) = ov;
    }
}

// ---------------------------------------------------------------------------
// Space attention (post-RoPE), MFMA flash-style.
// ---------------------------------------------------------------------------
__global__ __launch_bounds__(256) void attn_space_k(
    const bf16* __restrict__ QKV, bf16* __restrict__ AO)
{
    __shared__ __align__(16) bf16 KV[14336];      // 28KB: K blocked, then V blocked
    __shared__ __align__(16) bf16 Pb[4][3584];    // 28KB: per-wave P
    int g  = blockIdx.x;
    int qb = blockIdx.y;
    int bh = g >> 3, fi = g & 7;
    int b = bh >> 3, h = bh & 7;
    int tid = threadIdx.x;
    int w = tid >> 6, lane = tid & 63;
    int lm = lane & 15, lq = lane >> 4;

    // ---- stage K: 14 m-tiles x 2 k-chunks x 64 chunks = 1792 x 16B (7 iters)
    #pragma unroll
    for (int it = 0; it < 7; ++it) {
        int c = it*256 + tid;
        int mt  = c >> 7;
        int ks2 = (c >> 6) & 1;
        int lmc = (c >> 2) & 15;
        int lqc = c & 3;
        int key = mt*16 + lmc;
        int skey = (key < 2) ? key : ((key < 198) ? (2 + fi*NT + key - 2) : (2 + fi*NT));
        const bf16* src = QKV + ((size_t)(b*SEQ + skey))*1536 + 512 + h*64 + ks2*32 + lqc*8;
        __builtin_amdgcn_global_load_lds(
            (const __attribute__((address_space(1))) unsigned int*)src,
            (__attribute__((address_space(3))) unsigned int*)&KV[(it*256 + w*64)*8],
            16, 0, 0);
    }

    // ---- Q fragments (B-operand) straight from global
    int q0 = qb*64 + w*16;
    int qrow = q0 + lm; if (qrow > 195) qrow = 195;
    const bf16* qp = QKV + ((size_t)(b*SEQ + 2 + fi*NT + qrow))*1536 + h*64;
    bf16x8 bq0 = *(const bf16x8*)(qp + lq*8);
    bf16x8 bq1 = *(const bf16x8*)(qp + 32 + lq*8);

    __syncthreads();

    // ---- QK^T (S^T layout: row=key, col=q)
    f32x4 acc[14];
    #pragma unroll
    for (int mt = 0; mt < 14; ++mt) acc[mt] = (f32x4){0.f, 0.f, 0.f, 0.f};
    #pragma unroll
    for (int mt = 0; mt < 14; ++mt) {
        bf16x8 a0 = *(const bf16x8*)&KV[((mt*2 + 0)*64 + lm*4 + lq)*8];
        bf16x8 a1 = *(const bf16x8*)&KV[((mt*2 + 1)*64 + lm*4 + lq)*8];
        acc[mt] = __builtin_amdgcn_mfma_f32_16x16x32_bf16(a0, bq0, acc[mt], 0, 0, 0);
        acc[mt] = __builtin_amdgcn_mfma_f32_16x16x32_bf16(a1, bq1, acc[mt], 0, 0, 0);
    }

    // ---- softmax: lane q = q0+lm; keys = mt*16 + lq*4 + r
    int kbase = lq*4;
    float mx = -1e30f;
    #pragma unroll
    for (int mt = 0; mt < 14; ++mt)
        #pragma unroll
        for (int r = 0; r < 4; ++r) {
            int key = mt*16 + kbase + r;
            if (key < 198) mx = fmaxf(mx, acc[mt][r]*0.125f);
        }
    mx = fmaxf(mx, __shfl_xor(mx, 16));
    mx = fmaxf(mx, __shfl_xor(mx, 32));
    float sum = 0.f;
    #pragma unroll
    for (int mt = 0; mt < 14; ++mt)
        #pragma unroll
        for (int r = 0; r < 4; ++r) {
            int key = mt*16 + kbase + r;
            float p = (key < 198) ? expf(acc[mt][r]*0.125f - mx) : 0.f;
            acc[mt][r] = p;
            sum += p;
        }
    sum += __shfl_xor(sum, 16);
    sum += __shfl_xor(sum, 32);
    float inv = 1.f / sum;

    // ---- write P (bf16, normalized) to per-wave blocked buffer
    #pragma unroll
    for (int mt = 0; mt < 14; ++mt) {
        int K0 = mt*16 + kbase;
        int chunk = (K0 >> 5)*64 + lm*4 + ((K0 >> 3) & 3);
        bf16x4 pv;
        #pragma unroll
        for (int r = 0; r < 4; ++r) pv[r] = (bf16)(acc[mt][r] * inv);
        *(bf16x4*)&Pb[w][chunk*8 + (K0 & 7)] = pv;
    }
    __syncthreads();   // all waves done reading K from KV

    // ---- stage V into KV (blocked V^T-consumable layout), zero s>=198
    {
        int dchunk = tid >> 5, rr = tid & 31;
        #pragma unroll
        for (int si = 0; si < 7; ++si) {
            int s = si*32 + rr;
            bf16x8 vv;
            if (s < 198) {
                int sk = (s < 2) ? s : (2 + fi*NT + s - 2);
                vv = *(const bf16x8*)(QKV + ((size_t)(b*SEQ + sk))*1536 + 1024 + h*64 + dchunk*8);
            } else {
                #pragma unroll
                for (int e = 0; e < 8; ++e) vv[e] = (bf16)0.f;
            }
            int slot = rr >> 3, j2 = s & 7;
            #pragma unroll
            for (int j = 0; j < 8; ++j) {
                int d = dchunk*8 + j;
                KV[(((si*4 + (d >> 4))*16 + (d & 15))*4 + slot)*8 + j2] = vv[j];
            }
        }
    }
    __syncthreads();

    // ---- AV: O[q][d] = P x V^T
    f32x4 acc2[4];
    #pragma unroll
    for (int nt = 0; nt < 4; ++nt) acc2[nt] = (f32x4){0.f, 0.f, 0.f, 0.f};
    #pragma unroll
    for (int ks = 0; ks < 7; ++ks) {
        bf16x8 pa = *(const bf16x8*)&Pb[w][(ks*64 + lm*4 + lq)*8];
        #pragma unroll
        for (int nt = 0; nt < 4; ++nt) {
            bf16x8 bv = *(const bf16x8*)&KV[((((ks*4 + nt)*16 + lm)*4 + lq)*8)];
            acc2[nt] = __builtin_amdgcn_mfma_f32_16x16x32_bf16(pa, bv, acc2[nt], 0, 0, 0);
        }
    }

    // ---- store
    #pragma unroll
    for (int nt = 0; nt < 4; ++nt) {
        int d = nt*16 + lm;
        #pragma unroll
        for (int r = 0; r < 4; ++r) {
            int q = q0 + lq*4 + r;
            if (q < 196)
                AO[((size_t)(b*SEQ + 2 + fi*NT + q))*DM + h*64 + d] = (bf16)acc2[nt][r];
        }
    }
}

// ---------------------------------------------------------------------------
// Final head: LN(x[:,0]) @ out_W (512,2) + out_b -> f32 out (4,2)
// ---------------------------------------------------------------------------
__global__ __launch_bounds__(256) void final_head_k(
    const float* __restrict__ X, const float* __restrict__ g, const float* __restrict__ bt,
    const float* __restrict__ W, const float* __restrict__ bo, float* __restrict__ out)
{
    int b = blockIdx.x, tid = threadIdx.x;
    const float* x = X + (size_t)b * SEQ * DM;
    float v0 = x[tid], v1 = x[tid + 256];
    __shared__ float r1[256], r2[256];
    r1[tid] = v0 + v1;
    r2[tid] = v0*v0 + v1*v1;
    __syncthreads();
    for (int off = 128; off > 0; off >>= 1) {
        if (tid < off) { r1[tid] += r1[tid+off]; r2[tid] += r2[tid+off]; }
        __syncthreads();
    }
    float mean = r1[0] * (1.f / DM);
    float var  = r2[0] * (1.f / DM) - mean * mean;
    float inv  = rsqrtf(var + 1e-5f);
    float xn0 = (v0 - mean) * inv * g[tid]       + bt[tid];
    float xn1 = (v1 - mean) * inv * g[tid + 256] + bt[tid + 256];
    __syncthreads();
    r1[tid] = xn0 * W[tid*2]     + xn1 * W[(tid+256)*2];
    r2[tid] = xn0 * W[tid*2 + 1] + xn1 * W[(tid+256)*2 + 1];
    __syncthreads();
    for (int off = 128; off > 0; off >>= 1) {
        if (tid < off) { r1[tid] += r1[tid+off]; r2[tid] += r2[tid+off]; }
        __syncthreads();
    }
    if (tid == 0) {
        out[b*2 + 0] = r1[0] + bo[0];
        out[b*2 + 1] = r2[0] + bo[1];
    }
}

// ---------------------------------------------------------------------------
extern "C" void kernel_launch(void* const* d_in, const int* in_sizes, int n_in,
                              void* d_out, int out_size, void* d_ws, size_t ws_size,
                              hipStream_t stream)
{
    const float* video    = (const float*)d_in[0];
    const float* aa_w     = (const float*)d_in[1];
    const float* patch_W  = (const float*)d_in[2];
    const float* patch_b  = (const float*)d_in[3];
    const float* cls_tok  = (const float*)d_in[4];
    const float* aa_W     = (const float*)d_in[5];
    const float* aa_b     = (const float*)d_in[6];
    const float* ln_t_g   = (const float*)d_in[7];
    const float* ln_t_b   = (const float*)d_in[8];
    const float* t_qkv    = (const float*)d_in[9];
    const float* t_outW   = (const float*)d_in[10];
    const float* t_outb   = (const float*)d_in[11];
    const float* ln_s_g   = (const float*)d_in[12];
    const float* ln_s_b   = (const float*)d_in[13];
    const float* s_qkv    = (const float*)d_in[14];
    const float* s_outW   = (const float*)d_in[15];
    const float* s_outb   = (const float*)d_in[16];
    const float* ln_f_g   = (const float*)d_in[17];
    const float* ln_f_b   = (const float*)d_in[18];
    const float* ff_W1    = (const float*)d_in[19];
    const float* ff_b1    = (const float*)d_in[20];
    const float* ff_W2    = (const float*)d_in[21];
    const float* ff_b2    = (const float*)d_in[22];
    const float* out_ln_g = (const float*)d_in[23];
    const float* out_ln_b = (const float*)d_in[24];
    const float* out_W    = (const float*)d_in[25];
    const float* out_b    = (const float*)d_in[26];

    // ---- workspace layout ----
    char* p = (char*)d_ws;
    auto alloc = [&](size_t bytes) { char* r = p; p += (bytes + 255) & ~(size_t)255; return r; };
    float* X   = (float*)alloc((size_t)MR * DM * 4);
    bf16*  XN  = (bf16*)alloc((size_t)MR * DM * 2);
    bf16*  R   = (bf16*)alloc((size_t)MR * 4096 * 2);
    bf16*  B2  = (bf16*)alloc((size_t)MR * 2048 * 2);
    bf16*  Wt  = (bf16*)alloc((size_t)63307776 * 2);
    float* PART= (float*)alloc((size_t)64 * SPCH * 66 * 4);
    float* fsin = (float*)alloc(8*64*4);
    float* fcos = (float*)alloc(8*64*4);
    float* isin = (float*)alloc(196*64*4);
    float* icos = (float*)alloc(196*64*4);

    bf16* QKV = R;
    bf16* VP  = R;
    bf16* AO  = XN;

    bf16* patchW_t = Wt;
    bf16* tqkv_t   = patchW_t + 393216;
    bf16* toutW_t  = tqkv_t   + 9437184;
    bf16* sqkv_t   = toutW_t  + 3145728;
    bf16* soutW_t  = sqkv_t   + 9437184;
    bf16* ffW1_t   = soutW_t  + 3145728;
    bf16* ffW2_t   = ffW1_t   + 25165824;

    // ---- weight conversion ----
    dim3 wb(32, 8);
    wconv_k<<<dim3(1536/32, 512/32, 12), wb, 0, stream>>>(t_qkv,  tqkv_t,  512, 1536, 0);
    wconv_k<<<dim3( 512/32, 512/32, 12), wb, 0, stream>>>(t_outW, toutW_t, 512,  512, 0);
    wconv_k<<<dim3(1536/32, 512/32, 12), wb, 0, stream>>>(s_qkv,  sqkv_t,  512, 1536, 0);
    wconv_k<<<dim3( 512/32, 512/32, 12), wb, 0, stream>>>(s_outW, soutW_t, 512,  512, 0);
    wconv_k<<<dim3(4096/32, 512/32, 12), wb, 0, stream>>>(ff_W1,  ffW1_t,  512, 4096, 1);
    wconv_k<<<dim3( 512/32,2048/32, 12), wb, 0, stream>>>(ff_W2,  ffW2_t, 2048,  512, 0);
    wconv_k<<<dim3( 512/32, 768/32,  1), wb, 0, stream>>>(patch_W, patchW_t, 768, 512, 0);

    build_rot_k<<<25, 256, 0, stream>>>(fsin, fcos, isin, icos);

    // ---- patchify + token embedding ----
    patch_gather_k<<<(NB*NF*NT*768 + 255)/256, 256, 0, stream>>>(video, VP);
    init_special_k<<<(NB*DM + 255)/256, 256, 0, stream>>>(X, cls_tok, aa_w, aa_W, aa_b);
    gemm_mfma64<<<dim3(4, 98), 256, 0, stream>>>(
        VP, patchW_t, X, nullptr, patch_b, nullptr, 6272, 512, 768, 1);

    for (int l = 0; l < 12; ++l) {
        // ---- time attention ----
        layernorm_k<<<MR, 256, 0, stream>>>(X, XN, ln_t_g + l*DM, ln_t_b + l*DM);
        gemm_mfma<<<dim3(12, 50), 256, 0, stream>>>(
            XN, tqkv_t + (size_t)l*786432, nullptr, QKV, nullptr, nullptr, MR, 1536, 512, 0, 0);
        sp_part_k<<<dim3(32, SPCH), 256, 0, stream>>>(QKV, PART);
        sp_red_k<<<64, 64, 0, stream>>>(PART, AO);
        rope_k<<<6272, 256, 0, stream>>>(QKV, fsin, fcos, 0);
        attn_time_k<<<196, 256, 0, stream>>>(QKV, AO);
        gemm_mfma64<<<dim3(4, 99), 256, 0, stream>>>(
            AO, toutW_t + (size_t)l*262144, X, nullptr, t_outb + l*DM, X, MR, 512, 512, 0);

        // ---- space attention ----
        layernorm_k<<<MR, 256, 0, stream>>>(X, XN, ln_s_g + l*DM, ln_s_b + l*DM);
        gemm_mfma<<<dim3(12, 50), 256, 0, stream>>>(
            XN, sqkv_t + (size_t)l*786432, nullptr, QKV, nullptr, nullptr, MR, 1536, 512, 0, 0);
        sp_part_k<<<dim3(32, SPCH), 256, 0, stream>>>(QKV, PART);
        sp_red_k<<<64, 64, 0, stream>>>(PART, AO);
        rope_k<<<6272, 256, 0, stream>>>(QKV, isin, icos, 1);
        attn_space_k<<<dim3(256, 4), 256, 0, stream>>>(QKV, AO);
        gemm_mfma64<<<dim3(4, 99), 256, 0, stream>>>(
            AO, soutW_t + (size_t)l*262144, X, nullptr, s_outb + l*DM, X, MR, 512, 512, 0);

        // ---- GEGLU FF (gelu fused into FF1 epilogue via permuted W1) ----
        layernorm_k<<<MR, 256, 0, stream>>>(X, XN, ln_f_g + l*DM, ln_f_b + l*DM);
        gemm_mfma<<<dim3(32, 50), 256, 0, stream>>>(
            XN, ffW1_t + (size_t)l*2097152, nullptr, B2, ff_b1 + (size_t)l*4096, nullptr, MR, 4096, 512, 0, 1);
        gemm_mfma64<<<dim3(4, 99), 256, 0, stream>>>(
            B2, ffW2_t + (size_t)l*1048576, X, nullptr, ff_b2 + l*DM, X, MR, 512, 2048, 0);
    }

    final_head_k<<<NB, 256, 0, stream>>>(X, out_ln_g, out_ln_b, out_W, out_b, (float*)d_out);
}

// Round 5
// 4763.675 us; speedup vs baseline: 1.1092x; 1.0309x over previous
//
#include <hip/hip_runtime.h>
#include <math.h>

typedef __bf16 bf16;
typedef __bf16 bf16x8 __attribute__((ext_vector_type(8)));
typedef __bf16 bf16x4 __attribute__((ext_vector_type(4)));
typedef float  f32x4  __attribute__((ext_vector_type(4)));

#define SEQ   1570
#define NB    4
#define NF    8
#define NT    196
#define DM    512
#define MR    (NB*SEQ)   // 6280 rows
#define SPCH  13         // special-attn key chunks of 128

// ---------------------------------------------------------------------------
// Rotary tables
// ---------------------------------------------------------------------------
__global__ void build_rot_k(float* fsin, float* fcos, float* isin, float* icos)
{
    int tid = blockIdx.x * blockDim.x + threadIdx.x;
    if (tid < NF * 32) {
        int fi = tid >> 5, i = tid & 31;
        float inv = powf(10000.f, -(2.f * i) / 64.f);
        float v = fi * inv;
        float s = sinf(v), c = cosf(v);
        fsin[fi*64 + 2*i] = s; fsin[fi*64 + 2*i + 1] = s;
        fcos[fi*64 + 2*i] = c; fcos[fi*64 + 2*i + 1] = c;
    }
    if (tid < NT * 32) {
        int t = tid >> 5, i = tid & 31;
        int hi = t / 14, wi = t % 14;
        const float PI = 3.14159265358979323846f;
        float v;
        if (i < 16) {
            float scale = 1.f + 4.f * i / 15.f;
            v = (-1.f + 2.f * hi / 13.f) * scale * PI;
        } else {
            float scale = 1.f + 4.f * (i - 16) / 15.f;
            v = (-1.f + 2.f * wi / 13.f) * scale * PI;
        }
        float s = sinf(v), c = cosf(v);
        isin[t*64 + 2*i] = s; isin[t*64 + 2*i + 1] = s;
        icos[t*64 + 2*i] = c; icos[t*64 + 2*i + 1] = c;
    }
}

// ---------------------------------------------------------------------------
// Patchify: video (4,8,3,224,224) f32 -> VP (6272,768) bf16
// ---------------------------------------------------------------------------
__global__ void patch_gather_k(const float* __restrict__ video, bf16* __restrict__ VP)
{
    int idx = blockIdx.x * blockDim.x + threadIdx.x;
    if (idx >= NB * NF * NT * 768) return;
    int kk  = idx % 768;
    int row = (idx / 768) % (NF * NT);
    int b   = idx / (768 * NF * NT);
    int ch = kk % 3, pp = kk / 3;
    int pr = pp >> 4, pc = pp & 15;
    int fi = row / NT, t = row % NT;
    int hi = t / 14, wi = t % 14;
    size_t src = ((((size_t)b * NF + fi) * 3 + ch) * 224 + (hi*16 + pr)) * 224 + (wi*16 + pc);
    VP[idx] = (bf16)video[src];
}

// ---------------------------------------------------------------------------
// cls token + action-angle rows (fp32 X)
// ---------------------------------------------------------------------------
__global__ void init_special_k(float* X, const float* __restrict__ cls,
                               const float* __restrict__ aa_w,
                               const float* __restrict__ aa_W,
                               const float* __restrict__ aa_b)
{
    int idx = blockIdx.x * blockDim.x + threadIdx.x;
    if (idx >= NB * DM) return;
    int b = idx >> 9, d = idx & 511;
    X[(size_t)b * SEQ * DM + d] = cls[d];
    float acc = aa_b[d];
    for (int i = 0; i < 18; ++i) acc += aa_w[b*18 + i] * aa_W[i*DM + d];
    X[((size_t)b * SEQ + 1) * DM + d] = acc;
}

// ---------------------------------------------------------------------------
// Weight convert+transpose: W (L,K,N) f32 -> Wt (L,N,K) bf16
// gperm=1: GEGLU column permutation for FF1.
// ---------------------------------------------------------------------------
__global__ __launch_bounds__(256) void wconv_k(const float* __restrict__ W,
                                               bf16* __restrict__ Wt, int K, int N,
                                               int gperm)
{
    __shared__ float t[32][33];
    int bn = blockIdx.x;
    int n0dst = bn * 32;
    int n0src;
    if (gperm) n0src = ((bn & 1) * 2048) + ((bn >> 2) * 64) + (((bn >> 1) & 1) * 32);
    else       n0src = n0dst;
    int k0 = blockIdx.y * 32;
    const float* Wl = W + (size_t)blockIdx.z * K * N;
    bf16* Wtl = Wt + (size_t)blockIdx.z * K * N;
    #pragma unroll
    for (int i = 0; i < 4; ++i) {
        int k = k0 + threadIdx.y + i*8;
        t[threadIdx.y + i*8][threadIdx.x] = Wl[(size_t)k * N + n0src + threadIdx.x];
    }
    __syncthreads();
    #pragma unroll
    for (int i = 0; i < 4; ++i) {
        int n = n0dst + threadIdx.y + i*8;
        Wtl[(size_t)n * K + k0 + threadIdx.x] = (bf16)t[threadIdx.x][threadIdx.y + i*8];
    }
}

// ---------------------------------------------------------------------------
// MFMA GEMM: C[M,N] = A[M,K](bf16 row-major) * Bt[N,K](bf16 N-major)^T
// 128x128 tile, BK=32, double-buffered with COUNTED vmcnt (T3+T4): next
// tile's global_load_lds stay in flight across the barrier; never drain to
// 0 in the main loop. geglu=1: fused a*gelu(g) epilogue writing 2048 cols.
// ---------------------------------------------------------------------------
__global__ __launch_bounds__(256) void gemm_mfma(
    const bf16* __restrict__ A, const bf16* __restrict__ Bt,
    float* __restrict__ Cf, bf16* __restrict__ Cb,
    const float* __restrict__ bias, const float* __restrict__ resid,
    int M, int N, int K, int remap, int geglu)
{
    __shared__ bf16 As[2][128*32];
    __shared__ bf16 Bs[2][128*32];
    int tid  = threadIdx.x;
    int lane = tid & 63;
    int w    = tid >> 6;
    int wm = w >> 1, wn = w & 1;
    int rowBlk = blockIdx.y * 128, colBlk = blockIdx.x * 128;
    int lm = lane & 15, lq = lane >> 4;
    int sr  = lane >> 2;
    int sc8 = (lane & 3) * 8;

    f32x4 acc[4][4];
    #pragma unroll
    for (int i = 0; i < 4; ++i)
        #pragma unroll
        for (int j = 0; j < 4; ++j) acc[i][j] = (f32x4){0.f, 0.f, 0.f, 0.f};

    int ar0 = rowBlk + w*32 + sr;
    int br0 = colBlk + w*32 + sr;

    auto STAGE = [&](int buf, int k0) {
        #pragma unroll
        for (int c = 0; c < 2; ++c) {
            int ch = w*2 + c;
            int ar = ar0 + c*16; ar = (ar < M) ? ar : (M - 1);
            const bf16* ga = A + (size_t)ar * K + k0 + sc8;
            __builtin_amdgcn_global_load_lds(
                (const __attribute__((address_space(1))) unsigned int*)ga,
                (__attribute__((address_space(3))) unsigned int*)&As[buf][ch*16*32],
                16, 0, 0);
            int br = br0 + c*16;
            const bf16* gb = Bt + (size_t)br * K + k0 + sc8;
            __builtin_amdgcn_global_load_lds(
                (const __attribute__((address_space(1))) unsigned int*)gb,
                (__attribute__((address_space(3))) unsigned int*)&Bs[buf][ch*16*32],
                16, 0, 0);
        }
    };

    STAGE(0, 0);                 // 4 loads/thread in flight
    int nsteps = K >> 5;
    for (int t = 0; t < nsteps; ++t) {
        int cur = t & 1;
        if (t + 1 < nsteps) {
            STAGE(cur ^ 1, (t + 1) << 5);            // +4 loads (8 out)
            asm volatile("s_waitcnt vmcnt(4)" ::: "memory");  // wait cur's 4
        } else {
            asm volatile("s_waitcnt vmcnt(0)" ::: "memory");  // epilogue drain
        }
        __builtin_amdgcn_sched_barrier(0);
        __builtin_amdgcn_s_barrier();                // cur tile visible to all
        __builtin_amdgcn_sched_barrier(0);

        bf16x8 af[4], bfr[4];
        #pragma unroll
        for (int mt = 0; mt < 4; ++mt)
            af[mt] = *(const bf16x8*)&As[cur][(wm*64 + mt*16 + lm)*32 + lq*8];
        #pragma unroll
        for (int nt = 0; nt < 4; ++nt)
            bfr[nt] = *(const bf16x8*)&Bs[cur][(wn*64 + nt*16 + lm)*32 + lq*8];
        #pragma unroll
        for (int mt = 0; mt < 4; ++mt)
            #pragma unroll
            for (int nt = 0; nt < 4; ++nt)
                acc[mt][nt] = __builtin_amdgcn_mfma_f32_16x16x32_bf16(
                    af[mt], bfr[nt], acc[mt][nt], 0, 0, 0);

        __builtin_amdgcn_sched_barrier(0);
        __builtin_amdgcn_s_barrier();   // reads of cur done before overwrite
    }

    if (geglu) {
        #pragma unroll
        for (int nt = 0; nt < 2; ++nt) {
            int oa = (colBlk >> 1) + wn*32 + nt*16 + lm;   // 0..2047
            float ba = bias[oa], bg = bias[oa + 2048];
            #pragma unroll
            for (int mt = 0; mt < 4; ++mt) {
                #pragma unroll
                for (int r = 0; r < 4; ++r) {
                    int gm = rowBlk + wm*64 + mt*16 + lq*4 + r;
                    if (gm < M) {
                        float a = acc[mt][nt][r] + ba;
                        float g = acc[mt][nt+2][r] + bg;
                        float gl = 0.5f * g * (1.f + erff(g * 0.70710678118654752f));
                        Cb[(size_t)gm * 2048 + oa] = (bf16)(a * gl);
                    }
                }
            }
        }
        return;
    }

    #pragma unroll
    for (int nt = 0; nt < 4; ++nt) {
        int gn = colBlk + wn*64 + nt*16 + lm;
        float bs = bias ? bias[gn] : 0.f;
        #pragma unroll
        for (int mt = 0; mt < 4; ++mt) {
            #pragma unroll
            for (int r = 0; r < 4; ++r) {
                int gm = rowBlk + wm*64 + mt*16 + lq*4 + r;
                if (gm < M) {
                    int om = remap ? ((gm/1568)*1570 + 2 + (gm % 1568)) : gm;
                    size_t off = (size_t)om * N + gn;
                    float v = acc[mt][nt][r] + bs;
                    if (resid) v += resid[off];
                    if (Cf) Cf[off] = v;
                    else    Cb[off] = (bf16)v;
                }
            }
        }
    }
}

// ---------------------------------------------------------------------------
// M64 variant: 64x128 tile, BK=32, counted-vmcnt double-buffer (3 loads/
// thread/tile -> vmcnt(3)). For small-N GEMMs (out-proj, FF2, patch).
// ---------------------------------------------------------------------------
__global__ __launch_bounds__(256) void gemm_mfma64(
    const bf16* __restrict__ A, const bf16* __restrict__ Bt,
    float* __restrict__ Cf, bf16* __restrict__ Cb,
    const float* __restrict__ bias, const float* __restrict__ resid,
    int M, int N, int K, int remap)
{
    __shared__ bf16 As[2][64*32];
    __shared__ bf16 Bs[2][128*32];
    int tid  = threadIdx.x;
    int lane = tid & 63;
    int w    = tid >> 6;
    int wm = w >> 1, wn = w & 1;
    int rowBlk = blockIdx.y * 64, colBlk = blockIdx.x * 128;
    int lm = lane & 15, lq = lane >> 4;
    int sr  = lane >> 2;
    int sc8 = (lane & 3) * 8;

    f32x4 acc[2][4];
    #pragma unroll
    for (int i = 0; i < 2; ++i)
        #pragma unroll
        for (int j = 0; j < 4; ++j) acc[i][j] = (f32x4){0.f, 0.f, 0.f, 0.f};

    auto STAGE = [&](int buf, int k0) {
        {
            int ar = rowBlk + w*16 + sr;
            ar = (ar < M) ? ar : (M - 1);
            const bf16* ga = A + (size_t)ar * K + k0 + sc8;
            __builtin_amdgcn_global_load_lds(
                (const __attribute__((address_space(1))) unsigned int*)ga,
                (__attribute__((address_space(3))) unsigned int*)&As[buf][w*16*32],
                16, 0, 0);
        }
        #pragma unroll
        for (int c = 0; c < 2; ++c) {
            int ch = w*2 + c;
            int br = colBlk + ch*16 + sr;
            const bf16* gb = Bt + (size_t)br * K + k0 + sc8;
            __builtin_amdgcn_global_load_lds(
                (const __attribute__((address_space(1))) unsigned int*)gb,
                (__attribute__((address_space(3))) unsigned int*)&Bs[buf][ch*16*32],
                16, 0, 0);
        }
    };

    STAGE(0, 0);
    int nsteps = K >> 5;
    for (int t = 0; t < nsteps; ++t) {
        int cur = t & 1;
        if (t + 1 < nsteps) {
            STAGE(cur ^ 1, (t + 1) << 5);
            asm volatile("s_waitcnt vmcnt(3)" ::: "memory");
        } else {
            asm volatile("s_waitcnt vmcnt(0)" ::: "memory");
        }
        __builtin_amdgcn_sched_barrier(0);
        __builtin_amdgcn_s_barrier();
        __builtin_amdgcn_sched_barrier(0);

        bf16x8 af[2], bfr[4];
        #pragma unroll
        for (int mt = 0; mt < 2; ++mt)
            af[mt] = *(const bf16x8*)&As[cur][(wm*32 + mt*16 + lm)*32 + lq*8];
        #pragma unroll
        for (int nt = 0; nt < 4; ++nt)
            bfr[nt] = *(const bf16x8*)&Bs[cur][(wn*64 + nt*16 + lm)*32 + lq*8];
        #pragma unroll
        for (int mt = 0; mt < 2; ++mt)
            #pragma unroll
            for (int nt = 0; nt < 4; ++nt)
                acc[mt][nt] = __builtin_amdgcn_mfma_f32_16x16x32_bf16(
                    af[mt], bfr[nt], acc[mt][nt], 0, 0, 0);

        __builtin_amdgcn_sched_barrier(0);
        __builtin_amdgcn_s_barrier();
    }

    #pragma unroll
    for (int nt = 0; nt < 4; ++nt) {
        int gn = colBlk + wn*64 + nt*16 + lm;
        float bs = bias ? bias[gn] : 0.f;
        #pragma unroll
        for (int mt = 0; mt < 2; ++mt) {
            #pragma unroll
            for (int r = 0; r < 4; ++r) {
                int gm = rowBlk + wm*32 + mt*16 + lq*4 + r;
                if (gm < M) {
                    int om = remap ? ((gm/1568)*1570 + 2 + (gm % 1568)) : gm;
                    size_t off = (size_t)om * N + gn;
                    float v = acc[mt][nt][r] + bs;
                    if (resid) v += resid[off];
                    if (Cf) Cf[off] = v;
                    else    Cb[off] = (bf16)v;
                }
            }
        }
    }
}

// ---------------------------------------------------------------------------
// LayerNorm: X fp32 -> XN bf16 (wave shuffle reduce, 1 barrier)
// ---------------------------------------------------------------------------
__global__ __launch_bounds__(256) void layernorm_k(
    const float* __restrict__ X, bf16* __restrict__ XN,
    const float* __restrict__ g, const float* __restrict__ b)
{
    int row = blockIdx.x, tid = threadIdx.x;
    int wid = tid >> 6;
    const float* x = X + (size_t)row * DM;
    float v0 = x[tid], v1 = x[tid + 256];
    float s1 = v0 + v1, s2 = v0*v0 + v1*v1;
    #pragma unroll
    for (int off = 1; off < 64; off <<= 1) {
        s1 += __shfl_xor(s1, off);
        s2 += __shfl_xor(s2, off);
    }
    __shared__ float w1[4], w2[4];
    if ((tid & 63) == 0) { w1[wid] = s1; w2[wid] = s2; }
    __syncthreads();
    s1 = w1[0] + w1[1] + w1[2] + w1[3];
    s2 = w2[0] + w2[1] + w2[2] + w2[3];
    float mean = s1 * (1.f / DM);
    float var  = s2 * (1.f / DM) - mean * mean;
    float inv  = rsqrtf(var + 1e-5f);
    bf16* y = XN + (size_t)row * DM;
    y[tid]       = (bf16)((v0 - mean) * inv * g[tid]       + b[tid]);
    y[tid + 256] = (bf16)((v1 - mean) * inv * g[tid + 256] + b[tid + 256]);
}

// ---------------------------------------------------------------------------
// Special-token attention, partial pass: grid (32 bh, 13 chunks of 128 keys).
// ---------------------------------------------------------------------------
__global__ __launch_bounds__(256) void sp_part_k(
    const bf16* __restrict__ QKV, float* __restrict__ PART)
{
    __shared__ float q2[2][64];
    __shared__ float ps[2][128];
    __shared__ float red2[2][64];
    __shared__ float red[256];
    __shared__ float msh[2], dsh[2];
    int bh = blockIdx.x, ck = blockIdx.y;
    int b = bh >> 3, h = bh & 7;
    int tid = threadIdx.x;
    int k0 = ck * 128;

    if (tid < 128) {
        int qi = tid >> 6, d = tid & 63;
        q2[qi][d] = (float)QKV[((size_t)(b*SEQ + qi))*1536 + h*64 + d] * 0.125f;
    }
    __syncthreads();

    float s0 = -1e30f, s1 = -1e30f;
    int k = k0 + tid;
    if (tid < 128) {
        if (k < SEQ) {
            const bf16* kp = QKV + ((size_t)(b*SEQ + k))*1536 + 512 + h*64;
            s0 = 0.f; s1 = 0.f;
            #pragma unroll
            for (int c = 0; c < 8; ++c) {
                bf16x8 kv = *(const bf16x8*)(kp + c*8);
                #pragma unroll
                for (int e = 0; e < 8; ++e) {
                    float kf = (float)kv[e];
                    s0 += q2[0][c*8 + e] * kf;
                    s1 += q2[1][c*8 + e] * kf;
                }
            }
        }
        ps[0][tid] = s0; ps[1][tid] = s1;
    }
    __syncthreads();

    if (tid < 128) {
        int qi = tid >> 6, i = tid & 63;
        red2[qi][i] = fmaxf(ps[qi][i], ps[qi][i + 64]);
    }
    __syncthreads();
    for (int off = 32; off > 0; off >>= 1) {
        if (tid < 2*off) {
            int qi = (tid >= off) ? 1 : 0;
            int i = tid - qi*off;
            red2[qi][i] = fmaxf(red2[qi][i], red2[qi][i + off]);
        }
        __syncthreads();
    }
    if (tid < 2) msh[tid] = red2[tid][0];
    __syncthreads();
    float m0 = msh[0], m1 = msh[1];

    if (tid < 128) {
        float e0 = (k < SEQ) ? expf(s0 - m0) : 0.f;
        float e1 = (k < SEQ) ? expf(s1 - m1) : 0.f;
        ps[0][tid] = e0; ps[1][tid] = e1;
    }
    __syncthreads();
    if (tid < 128) {
        int qi = tid >> 6, i = tid & 63;
        red2[qi][i] = ps[qi][i] + ps[qi][i + 64];
    }
    __syncthreads();
    for (int off = 32; off > 0; off >>= 1) {
        if (tid < 2*off) {
            int qi = (tid >= off) ? 1 : 0;
            int i = tid - qi*off;
            red2[qi][i] += red2[qi][i + off];
        }
        __syncthreads();
    }
    if (tid < 2) dsh[tid] = red2[tid][0];
    __syncthreads();

    int d = tid & 63, kg = tid >> 6;
    float a0 = 0.f, a1 = 0.f;
    for (int kr = kg; kr < 128; kr += 4) {
        int kk = k0 + kr;
        if (kk < SEQ) {
            float vf = (float)QKV[((size_t)(b*SEQ + kk))*1536 + 1024 + h*64 + d];
            a0 += ps[0][kr] * vf;
            a1 += ps[1][kr] * vf;
        }
    }
    float* out = PART + ((size_t)(bh*2)*SPCH)*66;
    red[tid] = a0; __syncthreads();
    if (tid < 64) {
        float av = red[tid] + red[64+tid] + red[128+tid] + red[192+tid];
        out[(size_t)(0*SPCH + ck)*66 + 2 + tid] = av;
    }
    __syncthreads();
    red[tid] = a1; __syncthreads();
    if (tid < 64) {
        float av = red[tid] + red[64+tid] + red[128+tid] + red[192+tid];
        out[(size_t)(1*SPCH + ck)*66 + 2 + tid] = av;
    }
    if (tid < 2) {
        out[(size_t)(tid*SPCH + ck)*66 + 0] = msh[tid];
        out[(size_t)(tid*SPCH + ck)*66 + 1] = dsh[tid];
    }
}

// ---------------------------------------------------------------------------
// Special-token attention, reduce: grid 64 rows (bh*2+qi) x 64 threads (d).
// ---------------------------------------------------------------------------
__global__ __launch_bounds__(64) void sp_red_k(
    const float* __restrict__ PART, bf16* __restrict__ AO)
{
    int row = blockIdx.x;
    int bh = row >> 1, qi = row & 1;
    int b = bh >> 3, h = bh & 7;
    int d = threadIdx.x;
    const float* pr = PART + (size_t)row * SPCH * 66;
    float gm = -1e30f;
    #pragma unroll
    for (int c = 0; c < SPCH; ++c) gm = fmaxf(gm, pr[c*66]);
    float num = 0.f, den = 0.f;
    #pragma unroll
    for (int c = 0; c < SPCH; ++c) {
        float w = expf(pr[c*66] - gm);
        den += pr[c*66 + 1] * w;
        num += pr[c*66 + 2 + d] * w;
    }
    AO[((size_t)(b*SEQ + qi))*DM + h*64 + d] = (bf16)(num / den);
}

// ---------------------------------------------------------------------------
// In-place RoPE on q,k (bf16) for token rows >= 2
// ---------------------------------------------------------------------------
__global__ void rope_k(bf16* QKV, const float* __restrict__ sn,
                       const float* __restrict__ cs, int mode)
{
    int idx = blockIdx.x * blockDim.x + threadIdx.x;
    if (idx >= NB * NF * NT * 8 * 32) return;
    int p = idx & 31;
    int h = (idx >> 5) & 7;
    int t = (idx >> 8) % (NF * NT);
    int b = (idx >> 8) / (NF * NT);
    int ri = (mode == 0) ? (t / NT) : (t % NT);
    float c = cs[ri*64 + 2*p], s = sn[ri*64 + 2*p];
    size_t base = ((size_t)(b*SEQ + 2 + t)) * 1536 + h*64 + 2*p;
    float x0 = (float)QKV[base], x1 = (float)QKV[base + 1];
    QKV[base]     = (bf16)(x0 * c - x1 * s);
    QKV[base + 1] = (bf16)(x1 * c + x0 * s);
    base += 512;   // k
    x0 = (float)QKV[base]; x1 = (float)QKV[base + 1];
    QKV[base]     = (bf16)(x0 * c - x1 * s);
    QKV[base + 1] = (bf16)(x1 * c + x0 * s);
}

// ---------------------------------------------------------------------------
// Time attention (post-RoPE): one thread per q-row (b,h,jj,fq).
// 392 blocks x 128 threads so all 256 CUs get work.
// ---------------------------------------------------------------------------
__global__ __launch_bounds__(128) void attn_time_k(
    const bf16* __restrict__ QKV, bf16* __restrict__ AO)
{
    int rid = blockIdx.x * 128 + threadIdx.x;    // 392 blocks * 128 = 50176 exact
    int fq = rid & 7;
    int x  = rid >> 3;
    int jj = x % NT;
    int bh = x / NT;
    int b = bh >> 3, h = bh & 7;
    const bf16* qp = QKV + ((size_t)(b*SEQ + 2 + fq*NT + jj))*1536 + h*64;
    bf16x8 qv[8];
    #pragma unroll
    for (int c = 0; c < 8; ++c) qv[c] = *(const bf16x8*)(qp + c*8);
    float sc[10];
    #pragma unroll
    for (int j = 0; j < 10; ++j) {
        int krow = (j < 2) ? j : (2 + (j-2)*NT + jj);
        const bf16* kp = QKV + ((size_t)(b*SEQ + krow))*1536 + 512 + h*64;
        float s = 0.f;
        #pragma unroll
        for (int c = 0; c < 8; ++c) {
            bf16x8 kv = *(const bf16x8*)(kp + c*8);
            #pragma unroll
            for (int e = 0; e < 8; ++e) s += (float)qv[c][e] * (float)kv[e];
        }
        sc[j] = s * 0.125f;
    }
    float m = sc[0];
    #pragma unroll
    for (int j = 1; j < 10; ++j) m = fmaxf(m, sc[j]);
    float sum = 0.f;
    #pragma unroll
    for (int j = 0; j < 10; ++j) { sc[j] = expf(sc[j] - m); sum += sc[j]; }
    float inv = 1.f / sum;
    float out[64];
    #pragma unroll
    for (int d = 0; d < 64; ++d) out[d] = 0.f;
    #pragma unroll
    for (int j = 0; j < 10; ++j) {
        int vrow = (j < 2) ? j : (2 + (j-2)*NT + jj);
        const bf16* vp = QKV + ((size_t)(b*SEQ + vrow))*1536 + 1024 + h*64;
        float p = sc[j] * inv;
        #pragma unroll
        for (int c = 0; c < 8; ++c) {
            bf16x8 vv = *(const bf16x8*)(vp + c*8);
            #pragma unroll
            for (int e = 0; e < 8; ++e) out[c*8 + e] += p * (float)vv[e];
        }
    }
    bf16* op = AO + ((size_t)(b*SEQ + 2 + fq*NT + jj))*DM + h*64;
    #pragma unroll
    for (int c = 0; c < 8; ++c) {
        bf16x8 ov;
        #pragma unroll
        for (int e = 0; e < 8; ++e) ov[e] = (bf16)out[c*8 + e];
        *(bf16x8*)(op + c*8) = ov;
    }
}

// ---------------------------------------------------------------------------
// Space attention (post-RoPE), MFMA flash-style.
// ---------------------------------------------------------------------------
__global__ __launch_bounds__(256) void attn_space_k(
    const bf16* __restrict__ QKV, bf16* __restrict__ AO)
{
    __shared__ __align__(16) bf16 KV[14336];      // 28KB: K blocked, then V blocked
    __shared__ __align__(16) bf16 Pb[4][3584];    // 28KB: per-wave P
    int g  = blockIdx.x;
    int qb = blockIdx.y;
    int bh = g >> 3, fi = g & 7;
    int b = bh >> 3, h = bh & 7;
    int tid = threadIdx.x;
    int w = tid >> 6, lane = tid & 63;
    int lm = lane & 15, lq = lane >> 4;

    // ---- stage K: 14 m-tiles x 2 k-chunks x 64 chunks = 1792 x 16B (7 iters)
    #pragma unroll
    for (int it = 0; it < 7; ++it) {
        int c = it*256 + tid;
        int mt  = c >> 7;
        int ks2 = (c >> 6) & 1;
        int lmc = (c >> 2) & 15;
        int lqc = c & 3;
        int key = mt*16 + lmc;
        int skey = (key < 2) ? key : ((key < 198) ? (2 + fi*NT + key - 2) : (2 + fi*NT));
        const bf16* src = QKV + ((size_t)(b*SEQ + skey))*1536 + 512 + h*64 + ks2*32 + lqc*8;
        __builtin_amdgcn_global_load_lds(
            (const __attribute__((address_space(1))) unsigned int*)src,
            (__attribute__((address_space(3))) unsigned int*)&KV[(it*256 + w*64)*8],
            16, 0, 0);
    }

    // ---- Q fragments (B-operand) straight from global
    int q0 = qb*64 + w*16;
    int qrow = q0 + lm; if (qrow > 195) qrow = 195;
    const bf16* qp = QKV + ((size_t)(b*SEQ + 2 + fi*NT + qrow))*1536 + h*64;
    bf16x8 bq0 = *(const bf16x8*)(qp + lq*8);
    bf16x8 bq1 = *(const bf16x8*)(qp + 32 + lq*8);

    __syncthreads();

    // ---- QK^T (S^T layout: row=key, col=q)
    f32x4 acc[14];
    #pragma unroll
    for (int mt = 0; mt < 14; ++mt) acc[mt] = (f32x4){0.f, 0.f, 0.f, 0.f};
    #pragma unroll
    for (int mt = 0; mt < 14; ++mt) {
        bf16x8 a0 = *(const bf16x8*)&KV[((mt*2 + 0)*64 + lm*4 + lq)*8];
        bf16x8 a1 = *(const bf16x8*)&KV[((mt*2 + 1)*64 + lm*4 + lq)*8];
        acc[mt] = __builtin_amdgcn_mfma_f32_16x16x32_bf16(a0, bq0, acc[mt], 0, 0, 0);
        acc[mt] = __builtin_amdgcn_mfma_f32_16x16x32_bf16(a1, bq1, acc[mt], 0, 0, 0);
    }

    // ---- softmax: lane q = q0+lm; keys = mt*16 + lq*4 + r
    int kbase = lq*4;
    float mx = -1e30f;
    #pragma unroll
    for (int mt = 0; mt < 14; ++mt)
        #pragma unroll
        for (int r = 0; r < 4; ++r) {
            int key = mt*16 + kbase + r;
            if (key < 198) mx = fmaxf(mx, acc[mt][r]*0.125f);
        }
    mx = fmaxf(mx, __shfl_xor(mx, 16));
    mx = fmaxf(mx, __shfl_xor(mx, 32));
    float sum = 0.f;
    #pragma unroll
    for (int mt = 0; mt < 14; ++mt)
        #pragma unroll
        for (int r = 0; r < 4; ++r) {
            int key = mt*16 + kbase + r;
            float p = (key < 198) ? expf(acc[mt][r]*0.125f - mx) : 0.f;
            acc[mt][r] = p;
            sum += p;
        }
    sum += __shfl_xor(sum, 16);
    sum += __shfl_xor(sum, 32);
    float inv = 1.f / sum;

    // ---- write P (bf16, normalized) to per-wave blocked buffer
    #pragma unroll
    for (int mt = 0; mt < 14; ++mt) {
        int K0 = mt*16 + kbase;
        int chunk = (K0 >> 5)*64 + lm*4 + ((K0 >> 3) & 3);
        bf16x4 pv;
        #pragma unroll
        for (int r = 0; r < 4; ++r) pv[r] = (bf16)(acc[mt][r] * inv);
        *(bf16x4*)&Pb[w][chunk*8 + (K0 & 7)] = pv;
    }
    __syncthreads();   // all waves done reading K from KV

    // ---- stage V into KV (blocked V^T-consumable layout), zero s>=198
    {
        int dchunk = tid >> 5, rr = tid & 31;
        #pragma unroll
        for (int si = 0; si < 7; ++si) {
            int s = si*32 + rr;
            bf16x8 vv;
            if (s < 198) {
                int sk = (s < 2) ? s : (2 + fi*NT + s - 2);
                vv = *(const bf16x8*)(QKV + ((size_t)(b*SEQ + sk))*1536 + 1024 + h*64 + dchunk*8);
            } else {
                #pragma unroll
                for (int e = 0; e < 8; ++e) vv[e] = (bf16)0.f;
            }
            int slot = rr >> 3, j2 = s & 7;
            #pragma unroll
            for (int j = 0; j < 8; ++j) {
                int d = dchunk*8 + j;
                KV[(((si*4 + (d >> 4))*16 + (d & 15))*4 + slot)*8 + j2] = vv[j];
            }
        }
    }
    __syncthreads();

    // ---- AV: O[q][d] = P x V^T
    f32x4 acc2[4];
    #pragma unroll
    for (int nt = 0; nt < 4; ++nt) acc2[nt] = (f32x4){0.f, 0.f, 0.f, 0.f};
    #pragma unroll
    for (int ks = 0; ks < 7; ++ks) {
        bf16x8 pa = *(const bf16x8*)&Pb[w][(ks*64 + lm*4 + lq)*8];
        #pragma unroll
        for (int nt = 0; nt < 4; ++nt) {
            bf16x8 bv = *(const bf16x8*)&KV[((((ks*4 + nt)*16 + lm)*4 + lq)*8)];
            acc2[nt] = __builtin_amdgcn_mfma_f32_16x16x32_bf16(pa, bv, acc2[nt], 0, 0, 0);
        }
    }

    // ---- store
    #pragma unroll
    for (int nt = 0; nt < 4; ++nt) {
        int d = nt*16 + lm;
        #pragma unroll
        for (int r = 0; r < 4; ++r) {
            int q = q0 + lq*4 + r;
            if (q < 196)
                AO[((size_t)(b*SEQ + 2 + fi*NT + q))*DM + h*64 + d] = (bf16)acc2[nt][r];
        }
    }
}

// ---------------------------------------------------------------------------
// Final head: LN(x[:,0]) @ out_W (512,2) + out_b -> f32 out (4,2)
// ---------------------------------------------------------------------------
__global__ __launch_bounds__(256) void final_head_k(
    const float* __restrict__ X, const float* __restrict__ g, const float* __restrict__ bt,
    const float* __restrict__ W, const float* __restrict__ bo, float* __restrict__ out)
{
    int b = blockIdx.x, tid = threadIdx.x;
    const float* x = X + (size_t)b * SEQ * DM;
    float v0 = x[tid], v1 = x[tid + 256];
    __shared__ float r1[256], r2[256];
    r1[tid] = v0 + v1;
    r2[tid] = v0*v0 + v1*v1;
    __syncthreads();
    for (int off = 128; off > 0; off >>= 1) {
        if (tid < off) { r1[tid] += r1[tid+off]; r2[tid] += r2[tid+off]; }
        __syncthreads();
    }
    float mean = r1[0] * (1.f / DM);
    float var  = r2[0] * (1.f / DM) - mean * mean;
    float inv  = rsqrtf(var + 1e-5f);
    float xn0 = (v0 - mean) * inv * g[tid]       + bt[tid];
    float xn1 = (v1 - mean) * inv * g[tid + 256] + bt[tid + 256];
    __syncthreads();
    r1[tid] = xn0 * W[tid*2]     + xn1 * W[(tid+256)*2];
    r2[tid] = xn0 * W[tid*2 + 1] + xn1 * W[(tid+256)*2 + 1];
    __syncthreads();
    for (int off = 128; off > 0; off >>= 1) {
        if (tid < off) { r1[tid] += r1[tid+off]; r2[tid] += r2[tid+off]; }
        __syncthreads();
    }
    if (tid == 0) {
        out[b*2 + 0] = r1[0] + bo[0];
        out[b*2 + 1] = r2[0] + bo[1];
    }
}

// ---------------------------------------------------------------------------
extern "C" void kernel_launch(void* const* d_in, const int* in_sizes, int n_in,
                              void* d_out, int out_size, void* d_ws, size_t ws_size,
                              hipStream_t stream)
{
    const float* video    = (const float*)d_in[0];
    const float* aa_w     = (const float*)d_in[1];
    const float* patch_W  = (const float*)d_in[2];
    const float* patch_b  = (const float*)d_in[3];
    const float* cls_tok  = (const float*)d_in[4];
    const float* aa_W     = (const float*)d_in[5];
    const float* aa_b     = (const float*)d_in[6];
    const float* ln_t_g   = (const float*)d_in[7];
    const float* ln_t_b   = (const float*)d_in[8];
    const float* t_qkv    = (const float*)d_in[9];
    const float* t_outW   = (const float*)d_in[10];
    const float* t_outb   = (const float*)d_in[11];
    const float* ln_s_g   = (const float*)d_in[12];
    const float* ln_s_b   = (const float*)d_in[13];
    const float* s_qkv    = (const float*)d_in[14];
    const float* s_outW   = (const float*)d_in[15];
    const float* s_outb   = (const float*)d_in[16];
    const float* ln_f_g   = (const float*)d_in[17];
    const float* ln_f_b   = (const float*)d_in[18];
    const float* ff_W1    = (const float*)d_in[19];
    const float* ff_b1    = (const float*)d_in[20];
    const float* ff_W2    = (const float*)d_in[21];
    const float* ff_b2    = (const float*)d_in[22];
    const float* out_ln_g = (const float*)d_in[23];
    const float* out_ln_b = (const float*)d_in[24];
    const float* out_W    = (const float*)d_in[25];
    const float* out_b    = (const float*)d_in[26];

    // ---- workspace layout ----
    char* p = (char*)d_ws;
    auto alloc = [&](size_t bytes) { char* r = p; p += (bytes + 255) & ~(size_t)255; return r; };
    float* X   = (float*)alloc((size_t)MR * DM * 4);
    bf16*  XN  = (bf16*)alloc((size_t)MR * DM * 2);
    bf16*  R   = (bf16*)alloc((size_t)MR * 4096 * 2);
    bf16*  B2  = (bf16*)alloc((size_t)MR * 2048 * 2);
    bf16*  Wt  = (bf16*)alloc((size_t)63307776 * 2);
    float* PART= (float*)alloc((size_t)64 * SPCH * 66 * 4);
    float* fsin = (float*)alloc(8*64*4);
    float* fcos = (float*)alloc(8*64*4);
    float* isin = (float*)alloc(196*64*4);
    float* icos = (float*)alloc(196*64*4);

    bf16* QKV = R;
    bf16* VP  = R;
    bf16* AO  = XN;

    bf16* patchW_t = Wt;
    bf16* tqkv_t   = patchW_t + 393216;
    bf16* toutW_t  = tqkv_t   + 9437184;
    bf16* sqkv_t   = toutW_t  + 3145728;
    bf16* soutW_t  = sqkv_t   + 9437184;
    bf16* ffW1_t   = soutW_t  + 3145728;
    bf16* ffW2_t   = ffW1_t   + 25165824;

    // ---- weight conversion ----
    dim3 wb(32, 8);
    wconv_k<<<dim3(1536/32, 512/32, 12), wb, 0, stream>>>(t_qkv,  tqkv_t,  512, 1536, 0);
    wconv_k<<<dim3( 512/32, 512/32, 12), wb, 0, stream>>>(t_outW, toutW_t, 512,  512, 0);
    wconv_k<<<dim3(1536/32, 512/32, 12), wb, 0, stream>>>(s_qkv,  sqkv_t,  512, 1536, 0);
    wconv_k<<<dim3( 512/32, 512/32, 12), wb, 0, stream>>>(s_outW, soutW_t, 512,  512, 0);
    wconv_k<<<dim3(4096/32, 512/32, 12), wb, 0, stream>>>(ff_W1,  ffW1_t,  512, 4096, 1);
    wconv_k<<<dim3( 512/32,2048/32, 12), wb, 0, stream>>>(ff_W2,  ffW2_t, 2048,  512, 0);
    wconv_k<<<dim3( 512/32, 768/32,  1), wb, 0, stream>>>(patch_W, patchW_t, 768, 512, 0);

    build_rot_k<<<25, 256, 0, stream>>>(fsin, fcos, isin, icos);

    // ---- patchify + token embedding ----
    patch_gather_k<<<(NB*NF*NT*768 + 255)/256, 256, 0, stream>>>(video, VP);
    init_special_k<<<(NB*DM + 255)/256, 256, 0, stream>>>(X, cls_tok, aa_w, aa_W, aa_b);
    gemm_mfma64<<<dim3(4, 98), 256, 0, stream>>>(
        VP, patchW_t, X, nullptr, patch_b, nullptr, 6272, 512, 768, 1);

    for (int l = 0; l < 12; ++l) {
        // ---- time attention ----
        layernorm_k<<<MR, 256, 0, stream>>>(X, XN, ln_t_g + l*DM, ln_t_b + l*DM);
        gemm_mfma<<<dim3(12, 50), 256, 0, stream>>>(
            XN, tqkv_t + (size_t)l*786432, nullptr, QKV, nullptr, nullptr, MR, 1536, 512, 0, 0);
        sp_part_k<<<dim3(32, SPCH), 256, 0, stream>>>(QKV, PART);
        sp_red_k<<<64, 64, 0, stream>>>(PART, AO);
        rope_k<<<6272, 256, 0, stream>>>(QKV, fsin, fcos, 0);
        attn_time_k<<<392, 128, 0, stream>>>(QKV, AO);
        gemm_mfma64<<<dim3(4, 99), 256, 0, stream>>>(
            AO, toutW_t + (size_t)l*262144, X, nullptr, t_outb + l*DM, X, MR, 512, 512, 0);

        // ---- space attention ----
        layernorm_k<<<MR, 256, 0, stream>>>(X, XN, ln_s_g + l*DM, ln_s_b + l*DM);
        gemm_mfma<<<dim3(12, 50), 256, 0, stream>>>(
            XN, sqkv_t + (size_t)l*786432, nullptr, QKV, nullptr, nullptr, MR, 1536, 512, 0, 0);
        sp_part_k<<<dim3(32, SPCH), 256, 0, stream>>>(QKV, PART);
        sp_red_k<<<64, 64, 0, stream>>>(PART, AO);
        rope_k<<<6272, 256, 0, stream>>>(QKV, isin, icos, 1);
        attn_space_k<<<dim3(256, 4), 256, 0, stream>>>(QKV, AO);
        gemm_mfma64<<<dim3(4, 99), 256, 0, stream>>>(
            AO, soutW_t + (size_t)l*262144, X, nullptr, s_outb + l*DM, X, MR, 512, 512, 0);

        // ---- GEGLU FF (gelu fused into FF1 epilogue via permuted W1) ----
        layernorm_k<<<MR, 256, 0, stream>>>(X, XN, ln_f_g + l*DM, ln_f_b + l*DM);
        gemm_mfma<<<dim3(32, 50), 256, 0, stream>>>(
            XN, ffW1_t + (size_t)l*2097152, nullptr, B2, ff_b1 + (size_t)l*4096, nullptr, MR, 4096, 512, 0, 1);
        gemm_mfma64<<<dim3(4, 99), 256, 0, stream>>>(
            B2, ffW2_t + (size_t)l*1048576, X, nullptr, ff_b2 + l*DM, X, MR, 512, 2048, 0);
    }

    final_head_k<<<NB, 256, 0, stream>>>(X, out_ln_g, out_ln_b, out_W, out_b, (float*)d_out);
}

// Round 7
// 4648.451 us; speedup vs baseline: 1.1367x; 1.0248x over previous
//
#include <hip/hip_runtime.h>
#include <math.h>

typedef __bf16 bf16;
typedef __bf16 bf16x8 __attribute__((ext_vector_type(8)));
typedef __bf16 bf16x4 __attribute__((ext_vector_type(4)));
typedef float  f32x4  __attribute__((ext_vector_type(4)));

#define SEQ   1570
#define NB    4
#define NF    8
#define NT    196
#define DM    512
#define MR    (NB*SEQ)   // 6280 rows
#define SPCH  13         // special-attn key chunks of 128

// ---------------------------------------------------------------------------
// Rotary tables
// ---------------------------------------------------------------------------
__global__ void build_rot_k(float* fsin, float* fcos, float* isin, float* icos)
{
    int tid = blockIdx.x * blockDim.x + threadIdx.x;
    if (tid < NF * 32) {
        int fi = tid >> 5, i = tid & 31;
        float inv = powf(10000.f, -(2.f * i) / 64.f);
        float v = fi * inv;
        float s = sinf(v), c = cosf(v);
        fsin[fi*64 + 2*i] = s; fsin[fi*64 + 2*i + 1] = s;
        fcos[fi*64 + 2*i] = c; fcos[fi*64 + 2*i + 1] = c;
    }
    if (tid < NT * 32) {
        int t = tid >> 5, i = tid & 31;
        int hi = t / 14, wi = t % 14;
        const float PI = 3.14159265358979323846f;
        float v;
        if (i < 16) {
            float scale = 1.f + 4.f * i / 15.f;
            v = (-1.f + 2.f * hi / 13.f) * scale * PI;
        } else {
            float scale = 1.f + 4.f * (i - 16) / 15.f;
            v = (-1.f + 2.f * wi / 13.f) * scale * PI;
        }
        float s = sinf(v), c = cosf(v);
        isin[t*64 + 2*i] = s; isin[t*64 + 2*i + 1] = s;
        icos[t*64 + 2*i] = c; icos[t*64 + 2*i + 1] = c;
    }
}

// ---------------------------------------------------------------------------
// Patchify: video (4,8,3,224,224) f32 -> VP (6272,768) bf16
// ---------------------------------------------------------------------------
__global__ void patch_gather_k(const float* __restrict__ video, bf16* __restrict__ VP)
{
    int idx = blockIdx.x * blockDim.x + threadIdx.x;
    if (idx >= NB * NF * NT * 768) return;
    int kk  = idx % 768;
    int row = (idx / 768) % (NF * NT);
    int b   = idx / (768 * NF * NT);
    int ch = kk % 3, pp = kk / 3;
    int pr = pp >> 4, pc = pp & 15;
    int fi = row / NT, t = row % NT;
    int hi = t / 14, wi = t % 14;
    size_t src = ((((size_t)b * NF + fi) * 3 + ch) * 224 + (hi*16 + pr)) * 224 + (wi*16 + pc);
    VP[idx] = (bf16)video[src];
}

// ---------------------------------------------------------------------------
// cls token + action-angle rows (fp32 X)
// ---------------------------------------------------------------------------
__global__ void init_special_k(float* X, const float* __restrict__ cls,
                               const float* __restrict__ aa_w,
                               const float* __restrict__ aa_W,
                               const float* __restrict__ aa_b)
{
    int idx = blockIdx.x * blockDim.x + threadIdx.x;
    if (idx >= NB * DM) return;
    int b = idx >> 9, d = idx & 511;
    X[(size_t)b * SEQ * DM + d] = cls[d];
    float acc = aa_b[d];
    for (int i = 0; i < 18; ++i) acc += aa_w[b*18 + i] * aa_W[i*DM + d];
    X[((size_t)b * SEQ + 1) * DM + d] = acc;
}

// ---------------------------------------------------------------------------
// Weight convert+transpose: W (L,K,N) f32 -> Wt (L,N,K) bf16
// gperm=1: GEGLU column permutation for FF1.
// ---------------------------------------------------------------------------
__global__ __launch_bounds__(256) void wconv_k(const float* __restrict__ W,
                                               bf16* __restrict__ Wt, int K, int N,
                                               int gperm)
{
    __shared__ float t[32][33];
    int bn = blockIdx.x;
    int n0dst = bn * 32;
    int n0src;
    if (gperm) n0src = ((bn & 1) * 2048) + ((bn >> 2) * 64) + (((bn >> 1) & 1) * 32);
    else       n0src = n0dst;
    int k0 = blockIdx.y * 32;
    const float* Wl = W + (size_t)blockIdx.z * K * N;
    bf16* Wtl = Wt + (size_t)blockIdx.z * K * N;
    #pragma unroll
    for (int i = 0; i < 4; ++i) {
        int k = k0 + threadIdx.y + i*8;
        t[threadIdx.y + i*8][threadIdx.x] = Wl[(size_t)k * N + n0src + threadIdx.x];
    }
    __syncthreads();
    #pragma unroll
    for (int i = 0; i < 4; ++i) {
        int n = n0dst + threadIdx.y + i*8;
        Wtl[(size_t)n * K + k0 + threadIdx.x] = (bf16)t[threadIdx.x][threadIdx.y + i*8];
    }
}

// ---------------------------------------------------------------------------
// MFMA GEMM: C[M,N] = A[M,K](bf16 row-major) * Bt[N,K](bf16 N-major)^T
// 128x128 tile, BK=32, counted-vmcnt double-buffer.
// geglu=1: fused a*gelu(g) epilogue.
// KR!=null: QKV mode — fused RoPE epilogue. q roped in place (rows>=2),
// k written raw to Cb AND roped to KR, v raw. ropemode 0=time 1=space.
// ---------------------------------------------------------------------------
__global__ __launch_bounds__(256) void gemm_mfma(
    const bf16* __restrict__ A, const bf16* __restrict__ Bt,
    float* __restrict__ Cf, bf16* __restrict__ Cb,
    const float* __restrict__ bias, const float* __restrict__ resid,
    int M, int N, int K, int remap, int geglu,
    const float* __restrict__ rs, const float* __restrict__ rc,
    bf16* __restrict__ KR, int ropemode)
{
    __shared__ bf16 As[2][128*32];
    __shared__ bf16 Bs[2][128*32];
    int tid  = threadIdx.x;
    int lane = tid & 63;
    int w    = tid >> 6;
    int wm = w >> 1, wn = w & 1;
    int rowBlk = blockIdx.y * 128, colBlk = blockIdx.x * 128;
    int lm = lane & 15, lq = lane >> 4;
    int sr  = lane >> 2;
    int sc8 = (lane & 3) * 8;

    f32x4 acc[4][4];
    #pragma unroll
    for (int i = 0; i < 4; ++i)
        #pragma unroll
        for (int j = 0; j < 4; ++j) acc[i][j] = (f32x4){0.f, 0.f, 0.f, 0.f};

    int ar0 = rowBlk + w*32 + sr;
    int br0 = colBlk + w*32 + sr;

    auto STAGE = [&](int buf, int k0) {
        #pragma unroll
        for (int c = 0; c < 2; ++c) {
            int ch = w*2 + c;
            int ar = ar0 + c*16; ar = (ar < M) ? ar : (M - 1);
            const bf16* ga = A + (size_t)ar * K + k0 + sc8;
            __builtin_amdgcn_global_load_lds(
                (const __attribute__((address_space(1))) unsigned int*)ga,
                (__attribute__((address_space(3))) unsigned int*)&As[buf][ch*16*32],
                16, 0, 0);
            int br = br0 + c*16;
            const bf16* gb = Bt + (size_t)br * K + k0 + sc8;
            __builtin_amdgcn_global_load_lds(
                (const __attribute__((address_space(1))) unsigned int*)gb,
                (__attribute__((address_space(3))) unsigned int*)&Bs[buf][ch*16*32],
                16, 0, 0);
        }
    };

    STAGE(0, 0);
    int nsteps = K >> 5;
    for (int t = 0; t < nsteps; ++t) {
        int cur = t & 1;
        if (t + 1 < nsteps) {
            STAGE(cur ^ 1, (t + 1) << 5);
            asm volatile("s_waitcnt vmcnt(4)" ::: "memory");
        } else {
            asm volatile("s_waitcnt vmcnt(0)" ::: "memory");
        }
        __builtin_amdgcn_sched_barrier(0);
        __builtin_amdgcn_s_barrier();
        __builtin_amdgcn_sched_barrier(0);

        bf16x8 af[4], bfr[4];
        #pragma unroll
        for (int mt = 0; mt < 4; ++mt)
            af[mt] = *(const bf16x8*)&As[cur][(wm*64 + mt*16 + lm)*32 + lq*8];
        #pragma unroll
        for (int nt = 0; nt < 4; ++nt)
            bfr[nt] = *(const bf16x8*)&Bs[cur][(wn*64 + nt*16 + lm)*32 + lq*8];
        #pragma unroll
        for (int mt = 0; mt < 4; ++mt)
            #pragma unroll
            for (int nt = 0; nt < 4; ++nt)
                acc[mt][nt] = __builtin_amdgcn_mfma_f32_16x16x32_bf16(
                    af[mt], bfr[nt], acc[mt][nt], 0, 0, 0);

        __builtin_amdgcn_sched_barrier(0);
        __builtin_amdgcn_s_barrier();
    }

    if (KR) {   // fused-RoPE QKV epilogue
        #pragma unroll
        for (int nt = 0; nt < 4; ++nt) {
            int gn = colBlk + wn*64 + nt*16 + lm;
            int d = gn & 63;
            int seg = gn >> 9;   // 0=q, 1=k, 2=v
            #pragma unroll
            for (int mt = 0; mt < 4; ++mt) {
                #pragma unroll
                for (int r = 0; r < 4; ++r) {
                    int gm = rowBlk + wm*64 + mt*16 + lq*4 + r;
                    float v = acc[mt][nt][r];
                    float pv = __shfl_xor(v, 1);   // rotate-pair partner col
                    if (gm < M) {
                        int rb = gm % SEQ;
                        float ro = v;
                        if (seg < 2 && rb >= 2) {
                            int tk = rb - 2;
                            int ri = (ropemode == 0) ? (tk / NT) : (tk % NT);
                            float c = rc[ri*64 + d], s = rs[ri*64 + d];
                            ro = (d & 1) ? (v*c + pv*s) : (v*c - pv*s);
                        }
                        size_t off = (size_t)gm * N + gn;
                        Cb[off] = (bf16)((seg == 1) ? v : ro);   // k raw, q roped, v raw
                        if (seg == 1 && rb >= 2)
                            KR[(size_t)gm * 512 + (gn - 512)] = (bf16)ro;
                    }
                }
            }
        }
        return;
    }

    if (geglu) {
        #pragma unroll
        for (int nt = 0; nt < 2; ++nt) {
            int oa = (colBlk >> 1) + wn*32 + nt*16 + lm;   // 0..2047
            float ba = bias[oa], bg = bias[oa + 2048];
            #pragma unroll
            for (int mt = 0; mt < 4; ++mt) {
                #pragma unroll
                for (int r = 0; r < 4; ++r) {
                    int gm = rowBlk + wm*64 + mt*16 + lq*4 + r;
                    if (gm < M) {
                        float a = acc[mt][nt][r] + ba;
                        float g = acc[mt][nt+2][r] + bg;
                        float gl = 0.5f * g * (1.f + erff(g * 0.70710678118654752f));
                        Cb[(size_t)gm * 2048 + oa] = (bf16)(a * gl);
                    }
                }
            }
        }
        return;
    }

    #pragma unroll
    for (int nt = 0; nt < 4; ++nt) {
        int gn = colBlk + wn*64 + nt*16 + lm;
        float bs = bias ? bias[gn] : 0.f;
        #pragma unroll
        for (int mt = 0; mt < 4; ++mt) {
            #pragma unroll
            for (int r = 0; r < 4; ++r) {
                int gm = rowBlk + wm*64 + mt*16 + lq*4 + r;
                if (gm < M) {
                    int om = remap ? ((gm/1568)*1570 + 2 + (gm % 1568)) : gm;
                    size_t off = (size_t)om * N + gn;
                    float v = acc[mt][nt][r] + bs;
                    if (resid) v += resid[off];
                    if (Cf) Cf[off] = v;
                    else    Cb[off] = (bf16)v;
                }
            }
        }
    }
}

// ---------------------------------------------------------------------------
// M64 variant: 64x128 tile, BK=32, counted-vmcnt double-buffer.
// ---------------------------------------------------------------------------
__global__ __launch_bounds__(256) void gemm_mfma64(
    const bf16* __restrict__ A, const bf16* __restrict__ Bt,
    float* __restrict__ Cf, bf16* __restrict__ Cb,
    const float* __restrict__ bias, const float* __restrict__ resid,
    int M, int N, int K, int remap)
{
    __shared__ bf16 As[2][64*32];
    __shared__ bf16 Bs[2][128*32];
    int tid  = threadIdx.x;
    int lane = tid & 63;
    int w    = tid >> 6;
    int wm = w >> 1, wn = w & 1;
    int rowBlk = blockIdx.y * 64, colBlk = blockIdx.x * 128;
    int lm = lane & 15, lq = lane >> 4;
    int sr  = lane >> 2;
    int sc8 = (lane & 3) * 8;

    f32x4 acc[2][4];
    #pragma unroll
    for (int i = 0; i < 2; ++i)
        #pragma unroll
        for (int j = 0; j < 4; ++j) acc[i][j] = (f32x4){0.f, 0.f, 0.f, 0.f};

    auto STAGE = [&](int buf, int k0) {
        {
            int ar = rowBlk + w*16 + sr;
            ar = (ar < M) ? ar : (M - 1);
            const bf16* ga = A + (size_t)ar * K + k0 + sc8;
            __builtin_amdgcn_global_load_lds(
                (const __attribute__((address_space(1))) unsigned int*)ga,
                (__attribute__((address_space(3))) unsigned int*)&As[buf][w*16*32],
                16, 0, 0);
        }
        #pragma unroll
        for (int c = 0; c < 2; ++c) {
            int ch = w*2 + c;
            int br = colBlk + ch*16 + sr;
            const bf16* gb = Bt + (size_t)br * K + k0 + sc8;
            __builtin_amdgcn_global_load_lds(
                (const __attribute__((address_space(1))) unsigned int*)gb,
                (__attribute__((address_space(3))) unsigned int*)&Bs[buf][ch*16*32],
                16, 0, 0);
        }
    };

    STAGE(0, 0);
    int nsteps = K >> 5;
    for (int t = 0; t < nsteps; ++t) {
        int cur = t & 1;
        if (t + 1 < nsteps) {
            STAGE(cur ^ 1, (t + 1) << 5);
            asm volatile("s_waitcnt vmcnt(3)" ::: "memory");
        } else {
            asm volatile("s_waitcnt vmcnt(0)" ::: "memory");
        }
        __builtin_amdgcn_sched_barrier(0);
        __builtin_amdgcn_s_barrier();
        __builtin_amdgcn_sched_barrier(0);

        bf16x8 af[2], bfr[4];
        #pragma unroll
        for (int mt = 0; mt < 2; ++mt)
            af[mt] = *(const bf16x8*)&As[cur][(wm*32 + mt*16 + lm)*32 + lq*8];
        #pragma unroll
        for (int nt = 0; nt < 4; ++nt)
            bfr[nt] = *(const bf16x8*)&Bs[cur][(wn*64 + nt*16 + lm)*32 + lq*8];
        #pragma unroll
        for (int mt = 0; mt < 2; ++mt)
            #pragma unroll
            for (int nt = 0; nt < 4; ++nt)
                acc[mt][nt] = __builtin_amdgcn_mfma_f32_16x16x32_bf16(
                    af[mt], bfr[nt], acc[mt][nt], 0, 0, 0);

        __builtin_amdgcn_sched_barrier(0);
        __builtin_amdgcn_s_barrier();
    }

    #pragma unroll
    for (int nt = 0; nt < 4; ++nt) {
        int gn = colBlk + wn*64 + nt*16 + lm;
        float bs = bias ? bias[gn] : 0.f;
        #pragma unroll
        for (int mt = 0; mt < 2; ++mt) {
            #pragma unroll
            for (int r = 0; r < 4; ++r) {
                int gm = rowBlk + wm*32 + mt*16 + lq*4 + r;
                if (gm < M) {
                    int om = remap ? ((gm/1568)*1570 + 2 + (gm % 1568)) : gm;
                    size_t off = (size_t)om * N + gn;
                    float v = acc[mt][nt][r] + bs;
                    if (resid) v += resid[off];
                    if (Cf) Cf[off] = v;
                    else    Cb[off] = (bf16)v;
                }
            }
        }
    }
}

// ---------------------------------------------------------------------------
// LayerNorm: X fp32 -> XN bf16. One WAVE per row, float4 loads, shfl reduce,
// zero barriers. 4 rows/block, grid MR/4.
// ---------------------------------------------------------------------------
__global__ __launch_bounds__(256) void layernorm_k(
    const float* __restrict__ X, bf16* __restrict__ XN,
    const float* __restrict__ g, const float* __restrict__ b)
{
    int lane = threadIdx.x & 63;
    int row  = blockIdx.x * 4 + (threadIdx.x >> 6);
    const float* x = X + (size_t)row * DM;
    float4 v0 = *(const float4*)(x + lane*4);
    float4 v1 = *(const float4*)(x + 256 + lane*4);
    float s1 = v0.x+v0.y+v0.z+v0.w + v1.x+v1.y+v1.z+v1.w;
    float s2 = v0.x*v0.x+v0.y*v0.y+v0.z*v0.z+v0.w*v0.w
             + v1.x*v1.x+v1.y*v1.y+v1.z*v1.z+v1.w*v1.w;
    #pragma unroll
    for (int off = 1; off < 64; off <<= 1) {
        s1 += __shfl_xor(s1, off);
        s2 += __shfl_xor(s2, off);
    }
    float mean = s1 * (1.f / DM);
    float var  = s2 * (1.f / DM) - mean * mean;
    float inv  = rsqrtf(var + 1e-5f);
    float4 g0 = *(const float4*)(g + lane*4);
    float4 g1 = *(const float4*)(g + 256 + lane*4);
    float4 b0 = *(const float4*)(b + lane*4);
    float4 b1 = *(const float4*)(b + 256 + lane*4);
    bf16* y = XN + (size_t)row * DM;
    bf16x4 o0, o1;
    o0[0] = (bf16)((v0.x - mean)*inv*g0.x + b0.x);
    o0[1] = (bf16)((v0.y - mean)*inv*g0.y + b0.y);
    o0[2] = (bf16)((v0.z - mean)*inv*g0.z + b0.z);
    o0[3] = (bf16)((v0.w - mean)*inv*g0.w + b0.w);
    o1[0] = (bf16)((v1.x - mean)*inv*g1.x + b1.x);
    o1[1] = (bf16)((v1.y - mean)*inv*g1.y + b1.y);
    o1[2] = (bf16)((v1.z - mean)*inv*g1.z + b1.z);
    o1[3] = (bf16)((v1.w - mean)*inv*g1.w + b1.w);
    *(bf16x4*)(y + lane*4)       = o0;
    *(bf16x4*)(y + 256 + lane*4) = o1;
}

// ---------------------------------------------------------------------------
// Special-token attention, partial pass: grid (32 bh, 13 chunks of 128 keys).
// Reads RAW (pre-rope) k from QKV — reference semantics.
// ---------------------------------------------------------------------------
__global__ __launch_bounds__(256) void sp_part_k(
    const bf16* __restrict__ QKV, float* __restrict__ PART)
{
    __shared__ float q2[2][64];
    __shared__ float ps[2][128];
    __shared__ float red2[2][64];
    __shared__ float red[256];
    __shared__ float msh[2], dsh[2];
    int bh = blockIdx.x, ck = blockIdx.y;
    int b = bh >> 3, h = bh & 7;
    int tid = threadIdx.x;
    int k0 = ck * 128;

    if (tid < 128) {
        int qi = tid >> 6, d = tid & 63;
        q2[qi][d] = (float)QKV[((size_t)(b*SEQ + qi))*1536 + h*64 + d] * 0.125f;
    }
    __syncthreads();

    float s0 = -1e30f, s1 = -1e30f;
    int k = k0 + tid;
    if (tid < 128) {
        if (k < SEQ) {
            const bf16* kp = QKV + ((size_t)(b*SEQ + k))*1536 + 512 + h*64;
            s0 = 0.f; s1 = 0.f;
            #pragma unroll
            for (int c = 0; c < 8; ++c) {
                bf16x8 kv = *(const bf16x8*)(kp + c*8);
                #pragma unroll
                for (int e = 0; e < 8; ++e) {
                    float kf = (float)kv[e];
                    s0 += q2[0][c*8 + e] * kf;
                    s1 += q2[1][c*8 + e] * kf;
                }
            }
        }
        ps[0][tid] = s0; ps[1][tid] = s1;
    }
    __syncthreads();

    if (tid < 128) {
        int qi = tid >> 6, i = tid & 63;
        red2[qi][i] = fmaxf(ps[qi][i], ps[qi][i + 64]);
    }
    __syncthreads();
    for (int off = 32; off > 0; off >>= 1) {
        if (tid < 2*off) {
            int qi = (tid >= off) ? 1 : 0;
            int i = tid - qi*off;
            red2[qi][i] = fmaxf(red2[qi][i], red2[qi][i + off]);
        }
        __syncthreads();
    }
    if (tid < 2) msh[tid] = red2[tid][0];
    __syncthreads();
    float m0 = msh[0], m1 = msh[1];

    if (tid < 128) {
        float e0 = (k < SEQ) ? expf(s0 - m0) : 0.f;
        float e1 = (k < SEQ) ? expf(s1 - m1) : 0.f;
        ps[0][tid] = e0; ps[1][tid] = e1;
    }
    __syncthreads();
    if (tid < 128) {
        int qi = tid >> 6, i = tid & 63;
        red2[qi][i] = ps[qi][i] + ps[qi][i + 64];
    }
    __syncthreads();
    for (int off = 32; off > 0; off >>= 1) {
        if (tid < 2*off) {
            int qi = (tid >= off) ? 1 : 0;
            int i = tid - qi*off;
            red2[qi][i] += red2[qi][i + off];
        }
        __syncthreads();
    }
    if (tid < 2) dsh[tid] = red2[tid][0];
    __syncthreads();

    int d = tid & 63, kg = tid >> 6;
    float a0 = 0.f, a1 = 0.f;
    for (int kr = kg; kr < 128; kr += 4) {
        int kk = k0 + kr;
        if (kk < SEQ) {
            float vf = (float)QKV[((size_t)(b*SEQ + kk))*1536 + 1024 + h*64 + d];
            a0 += ps[0][kr] * vf;
            a1 += ps[1][kr] * vf;
        }
    }
    float* out = PART + ((size_t)(bh*2)*SPCH)*66;
    red[tid] = a0; __syncthreads();
    if (tid < 64) {
        float av = red[tid] + red[64+tid] + red[128+tid] + red[192+tid];
        out[(size_t)(0*SPCH + ck)*66 + 2 + tid] = av;
    }
    __syncthreads();
    red[tid] = a1; __syncthreads();
    if (tid < 64) {
        float av = red[tid] + red[64+tid] + red[128+tid] + red[192+tid];
        out[(size_t)(1*SPCH + ck)*66 + 2 + tid] = av;
    }
    if (tid < 2) {
        out[(size_t)(tid*SPCH + ck)*66 + 0] = msh[tid];
        out[(size_t)(tid*SPCH + ck)*66 + 1] = dsh[tid];
    }
}

// ---------------------------------------------------------------------------
// Special-token attention, reduce: grid 64 rows (bh*2+qi) x 64 threads (d).
// ---------------------------------------------------------------------------
__global__ __launch_bounds__(64) void sp_red_k(
    const float* __restrict__ PART, bf16* __restrict__ AO)
{
    int row = blockIdx.x;
    int bh = row >> 1, qi = row & 1;
    int b = bh >> 3, h = bh & 7;
    int d = threadIdx.x;
    const float* pr = PART + (size_t)row * SPCH * 66;
    float gm = -1e30f;
    #pragma unroll
    for (int c = 0; c < SPCH; ++c) gm = fmaxf(gm, pr[c*66]);
    float num = 0.f, den = 0.f;
    #pragma unroll
    for (int c = 0; c < SPCH; ++c) {
        float w = expf(pr[c*66] - gm);
        den += pr[c*66 + 1] * w;
        num += pr[c*66 + 2 + d] * w;
    }
    AO[((size_t)(b*SEQ + qi))*DM + h*64 + d] = (bf16)(num / den);
}

// ---------------------------------------------------------------------------
// Time attention: one thread per q-row. q roped in QKV; token keys from KR.
// ---------------------------------------------------------------------------
__global__ __launch_bounds__(128) void attn_time_k(
    const bf16* __restrict__ QKV, const bf16* __restrict__ KR,
    bf16* __restrict__ AO)
{
    int rid = blockIdx.x * 128 + threadIdx.x;    // 392 blocks * 128 = 50176 exact
    int fq = rid & 7;
    int x  = rid >> 3;
    int jj = x % NT;
    int bh = x / NT;
    int b = bh >> 3, h = bh & 7;
    const bf16* qp = QKV + ((size_t)(b*SEQ + 2 + fq*NT + jj))*1536 + h*64;
    bf16x8 qv[8];
    #pragma unroll
    for (int c = 0; c < 8; ++c) qv[c] = *(const bf16x8*)(qp + c*8);
    float sc[10];
    #pragma unroll
    for (int j = 0; j < 10; ++j) {
        int krow = (j < 2) ? j : (2 + (j-2)*NT + jj);
        const bf16* kp = (j < 2)
            ? QKV + ((size_t)(b*SEQ + krow))*1536 + 512 + h*64
            : KR  + ((size_t)(b*SEQ + krow))*512 + h*64;
        float s = 0.f;
        #pragma unroll
        for (int c = 0; c < 8; ++c) {
            bf16x8 kv = *(const bf16x8*)(kp + c*8);
            #pragma unroll
            for (int e = 0; e < 8; ++e) s += (float)qv[c][e] * (float)kv[e];
        }
        sc[j] = s * 0.125f;
    }
    float m = sc[0];
    #pragma unroll
    for (int j = 1; j < 10; ++j) m = fmaxf(m, sc[j]);
    float sum = 0.f;
    #pragma unroll
    for (int j = 0; j < 10; ++j) { sc[j] = expf(sc[j] - m); sum += sc[j]; }
    float inv = 1.f / sum;
    float out[64];
    #pragma unroll
    for (int d = 0; d < 64; ++d) out[d] = 0.f;
    #pragma unroll
    for (int j = 0; j < 10; ++j) {
        int vrow = (j < 2) ? j : (2 + (j-2)*NT + jj);
        const bf16* vp = QKV + ((size_t)(b*SEQ + vrow))*1536 + 1024 + h*64;
        float p = sc[j] * inv;
        #pragma unroll
        for (int c = 0; c < 8; ++c) {
            bf16x8 vv = *(const bf16x8*)(vp + c*8);
            #pragma unroll
            for (int e = 0; e < 8; ++e) out[c*8 + e] += p * (float)vv[e];
        }
    }
    bf16* op = AO + ((size_t)(b*SEQ + 2 + fq*NT + jj))*DM + h*64;
    #pragma unroll
    for (int c = 0; c < 8; ++c) {
        bf16x8 ov;
        #pragma unroll
        for (int e = 0; e < 8; ++e) ov[e] = (bf16)out[c*8 + e];
        *(bf16x8*)(op + c*8) = ov;
    }
}

// ---------------------------------------------------------------------------
// Space attention, MFMA flash-style. Token keys staged from KR (roped).
// ---------------------------------------------------------------------------
__global__ __launch_bounds__(256) void attn_space_k(
    const bf16* __restrict__ QKV, const bf16* __restrict__ KR,
    bf16* __restrict__ AO)
{
    __shared__ __align__(16) bf16 KV[14336];      // 28KB: K blocked, then V blocked
    __shared__ __align__(16) bf16 Pb[4][3584];    // 28KB: per-wave P
    int g  = blockIdx.x;
    int qb = blockIdx.y;
    int bh = g >> 3, fi = g & 7;
    int b = bh >> 3, h = bh & 7;
    int tid = threadIdx.x;
    int w = tid >> 6, lane = tid & 63;
    int lm = lane & 15, lq = lane >> 4;

    // ---- stage K: 14 m-tiles x 2 k-chunks x 64 chunks = 1792 x 16B (7 iters)
    #pragma unroll
    for (int it = 0; it < 7; ++it) {
        int c = it*256 + tid;
        int mt  = c >> 7;
        int ks2 = (c >> 6) & 1;
        int lmc = (c >> 2) & 15;
        int lqc = c & 3;
        int key = mt*16 + lmc;
        int skey = (key < 2) ? key : ((key < 198) ? (2 + fi*NT + key - 2) : (2 + fi*NT));
        const bf16* src = (key < 2)
            ? QKV + ((size_t)(b*SEQ + skey))*1536 + 512 + h*64 + ks2*32 + lqc*8
            : KR  + ((size_t)(b*SEQ + skey))*512 + h*64 + ks2*32 + lqc*8;
        __builtin_amdgcn_global_load_lds(
            (const __attribute__((address_space(1))) unsigned int*)src,
            (__attribute__((address_space(3))) unsigned int*)&KV[(it*256 + w*64)*8],
            16, 0, 0);
    }

    // ---- Q fragments (B-operand) straight from global (pre-roped)
    int q0 = qb*64 + w*16;
    int qrow = q0 + lm; if (qrow > 195) qrow = 195;
    const bf16* qp = QKV + ((size_t)(b*SEQ + 2 + fi*NT + qrow))*1536 + h*64;
    bf16x8 bq0 = *(const bf16x8*)(qp + lq*8);
    bf16x8 bq1 = *(const bf16x8*)(qp + 32 + lq*8);

    __syncthreads();

    // ---- QK^T (S^T layout: row=key, col=q)
    f32x4 acc[14];
    #pragma unroll
    for (int mt = 0; mt < 14; ++mt) acc[mt] = (f32x4){0.f, 0.f, 0.f, 0.f};
    #pragma unroll
    for (int mt = 0; mt < 14; ++mt) {
        bf16x8 a0 = *(const bf16x8*)&KV[((mt*2 + 0)*64 + lm*4 + lq)*8];
        bf16x8 a1 = *(const bf16x8*)&KV[((mt*2 + 1)*64 + lm*4 + lq)*8];
        acc[mt] = __builtin_amdgcn_mfma_f32_16x16x32_bf16(a0, bq0, acc[mt], 0, 0, 0);
        acc[mt] = __builtin_amdgcn_mfma_f32_16x16x32_bf16(a1, bq1, acc[mt], 0, 0, 0);
    }

    // ---- softmax: lane q = q0+lm; keys = mt*16 + lq*4 + r
    int kbase = lq*4;
    float mx = -1e30f;
    #pragma unroll
    for (int mt = 0; mt < 14; ++mt)
        #pragma unroll
        for (int r = 0; r < 4; ++r) {
            int key = mt*16 + kbase + r;
            if (key < 198) mx = fmaxf(mx, acc[mt][r]*0.125f);
        }
    mx = fmaxf(mx, __shfl_xor(mx, 16));
    mx = fmaxf(mx, __shfl_xor(mx, 32));
    float sum = 0.f;
    #pragma unroll
    for (int mt = 0; mt < 14; ++mt)
        #pragma unroll
        for (int r = 0; r < 4; ++r) {
            int key = mt*16 + kbase + r;
            float p = (key < 198) ? expf(acc[mt][r]*0.125f - mx) : 0.f;
            acc[mt][r] = p;
            sum += p;
        }
    sum += __shfl_xor(sum, 16);
    sum += __shfl_xor(sum, 32);
    float inv = 1.f / sum;

    // ---- write P (bf16, normalized) to per-wave blocked buffer
    #pragma unroll
    for (int mt = 0; mt < 14; ++mt) {
        int K0 = mt*16 + kbase;
        int chunk = (K0 >> 5)*64 + lm*4 + ((K0 >> 3) & 3);
        bf16x4 pv;
        #pragma unroll
        for (int r = 0; r < 4; ++r) pv[r] = (bf16)(acc[mt][r] * inv);
        *(bf16x4*)&Pb[w][chunk*8 + (K0 & 7)] = pv;
    }
    __syncthreads();   // all waves done reading K from KV

    // ---- stage V into KV (blocked V^T-consumable layout), zero s>=198
    {
        int dchunk = tid >> 5, rr = tid & 31;
        #pragma unroll
        for (int si = 0; si < 7; ++si) {
            int s = si*32 + rr;
            bf16x8 vv;
            if (s < 198) {
                int sk = (s < 2) ? s : (2 + fi*NT + s - 2);
                vv = *(const bf16x8*)(QKV + ((size_t)(b*SEQ + sk))*1536 + 1024 + h*64 + dchunk*8);
            } else {
                #pragma unroll
                for (int e = 0; e < 8; ++e) vv[e] = (bf16)0.f;
            }
            int slot = rr >> 3, j2 = s & 7;
            #pragma unroll
            for (int j = 0; j < 8; ++j) {
                int d = dchunk*8 + j;
                KV[(((si*4 + (d >> 4))*16 + (d & 15))*4 + slot)*8 + j2] = vv[j];
            }
        }
    }
    __syncthreads();

    // ---- AV: O[q][d] = P x V^T
    f32x4 acc2[4];
    #pragma unroll
    for (int nt = 0; nt < 4; ++nt) acc2[nt] = (f32x4){0.f, 0.f, 0.f, 0.f};
    #pragma unroll
    for (int ks = 0; ks < 7; ++ks) {
        bf16x8 pa = *(const bf16x8*)&Pb[w][(ks*64 + lm*4 + lq)*8];
        #pragma unroll
        for (int nt = 0; nt < 4; ++nt) {
            bf16x8 bv = *(const bf16x8*)&KV[((((ks*4 + nt)*16 + lm)*4 + lq)*8)];
            acc2[nt] = __builtin_amdgcn_mfma_f32_16x16x32_bf16(pa, bv, acc2[nt], 0, 0, 0);
        }
    }

    // ---- store
    #pragma unroll
    for (int nt = 0; nt < 4; ++nt) {
        int d = nt*16 + lm;
        #pragma unroll
        for (int r = 0; r < 4; ++r) {
            int q = q0 + lq*4 + r;
            if (q < 196)
                AO[((size_t)(b*SEQ + 2 + fi*NT + q))*DM + h*64 + d] = (bf16)acc2[nt][r];
        }
    }
}

// ---------------------------------------------------------------------------
// Final head: LN(x[:,0]) @ out_W (512,2) + out_b -> f32 out (4,2)
// ---------------------------------------------------------------------------
__global__ __launch_bounds__(256) void final_head_k(
    const float* __restrict__ X, const float* __restrict__ g, const float* __restrict__ bt,
    const float* __restrict__ W, const float* __restrict__ bo, float* __restrict__ out)
{
    int b = blockIdx.x, tid = threadIdx.x;
    const float* x = X + (size_t)b * SEQ * DM;
    float v0 = x[tid], v1 = x[tid + 256];
    __shared__ float r1[256], r2[256];
    r1[tid] = v0 + v1;
    r2[tid] = v0*v0 + v1*v1;
    __syncthreads();
    for (int off = 128; off > 0; off >>= 1) {
        if (tid < off) { r1[tid] += r1[tid+off]; r2[tid] += r2[tid+off]; }
        __syncthreads();
    }
    float mean = r1[0] * (1.f / DM);
    float var  = r2[0] * (1.f / DM) - mean * mean;
    float inv  = rsqrtf(var + 1e-5f);
    float xn0 = (v0 - mean) * inv * g[tid]       + bt[tid];
    float xn1 = (v1 - mean) * inv * g[tid + 256] + bt[tid + 256];
    __syncthreads();
    r1[tid] = xn0 * W[tid*2]     + xn1 * W[(tid+256)*2];
    r2[tid] = xn0 * W[tid*2 + 1] + xn1 * W[(tid+256)*2 + 1];
    __syncthreads();
    for (int off = 128; off > 0; off >>= 1) {
        if (tid < off) { r1[tid] += r1[tid+off]; r2[tid] += r2[tid+off]; }
        __syncthreads();
    }
    if (tid == 0) {
        out[b*2 + 0] = r1[0] + bo[0];
        out[b*2 + 1] = r2[0] + bo[1];
    }
}

// ---------------------------------------------------------------------------
extern "C" void kernel_launch(void* const* d_in, const int* in_sizes, int n_in,
                              void* d_out, int out_size, void* d_ws, size_t ws_size,
                              hipStream_t stream)
{
    const float* video    = (const float*)d_in[0];
    const float* aa_w     = (const float*)d_in[1];
    const float* patch_W  = (const float*)d_in[2];
    const float* patch_b  = (const float*)d_in[3];
    const float* cls_tok  = (const float*)d_in[4];
    const float* aa_W     = (const float*)d_in[5];
    const float* aa_b     = (const float*)d_in[6];
    const float* ln_t_g   = (const float*)d_in[7];
    const float* ln_t_b   = (const float*)d_in[8];
    const float* t_qkv    = (const float*)d_in[9];
    const float* t_outW   = (const float*)d_in[10];
    const float* t_outb   = (const float*)d_in[11];
    const float* ln_s_g   = (const float*)d_in[12];
    const float* ln_s_b   = (const float*)d_in[13];
    const float* s_qkv    = (const float*)d_in[14];
    const float* s_outW   = (const float*)d_in[15];
    const float* s_outb   = (const float*)d_in[16];
    const float* ln_f_g   = (const float*)d_in[17];
    const float* ln_f_b   = (const float*)d_in[18];
    const float* ff_W1    = (const float*)d_in[19];
    const float* ff_b1    = (const float*)d_in[20];
    const float* ff_W2    = (const float*)d_in[21];
    const float* ff_b2    = (const float*)d_in[22];
    const float* out_ln_g = (const float*)d_in[23];
    const float* out_ln_b = (const float*)d_in[24];
    const float* out_W    = (const float*)d_in[25];
    const float* out_b    = (const float*)d_in[26];

    // ---- workspace layout ----
    char* p = (char*)d_ws;
    auto alloc = [&](size_t bytes) { char* r = p; p += (bytes + 255) & ~(size_t)255; return r; };
    float* X   = (float*)alloc((size_t)MR * DM * 4);
    bf16*  XN  = (bf16*)alloc((size_t)MR * DM * 2);
    bf16*  R   = (bf16*)alloc((size_t)MR * 4096 * 2);
    bf16*  B2  = (bf16*)alloc((size_t)MR * 2048 * 2);
    bf16*  Wt  = (bf16*)alloc((size_t)63307776 * 2);
    float* PART= (float*)alloc((size_t)64 * SPCH * 66 * 4);
    float* fsin = (float*)alloc(8*64*4);
    float* fcos = (float*)alloc(8*64*4);
    float* isin = (float*)alloc(196*64*4);
    float* icos = (float*)alloc(196*64*4);

    bf16* QKV = R;
    bf16* VP  = R;
    bf16* AO  = XN;
    bf16* KR  = B2;   // alias: B2 (FF1->FF2) and KR (QKV->attn) have disjoint lifetimes

    bf16* patchW_t = Wt;
    bf16* tqkv_t   = patchW_t + 393216;
    bf16* toutW_t  = tqkv_t   + 9437184;
    bf16* sqkv_t   = toutW_t  + 3145728;
    bf16* soutW_t  = sqkv_t   + 9437184;
    bf16* ffW1_t   = soutW_t  + 3145728;
    bf16* ffW2_t   = ffW1_t   + 25165824;

    // ---- weight conversion ----
    dim3 wb(32, 8);
    wconv_k<<<dim3(1536/32, 512/32, 12), wb, 0, stream>>>(t_qkv,  tqkv_t,  512, 1536, 0);
    wconv_k<<<dim3( 512/32, 512/32, 12), wb, 0, stream>>>(t_outW, toutW_t, 512,  512, 0);
    wconv_k<<<dim3(1536/32, 512/32, 12), wb, 0, stream>>>(s_qkv,  sqkv_t,  512, 1536, 0);
    wconv_k<<<dim3( 512/32, 512/32, 12), wb, 0, stream>>>(s_outW, soutW_t, 512,  512, 0);
    wconv_k<<<dim3(4096/32, 512/32, 12), wb, 0, stream>>>(ff_W1,  ffW1_t,  512, 4096, 1);
    wconv_k<<<dim3( 512/32,2048/32, 12), wb, 0, stream>>>(ff_W2,  ffW2_t, 2048,  512, 0);
    wconv_k<<<dim3( 512/32, 768/32,  1), wb, 0, stream>>>(patch_W, patchW_t, 768, 512, 0);

    build_rot_k<<<25, 256, 0, stream>>>(fsin, fcos, isin, icos);

    // ---- patchify + token embedding ----
    patch_gather_k<<<(NB*NF*NT*768 + 255)/256, 256, 0, stream>>>(video, VP);
    init_special_k<<<(NB*DM + 255)/256, 256, 0, stream>>>(X, cls_tok, aa_w, aa_W, aa_b);
    gemm_mfma64<<<dim3(4, 98), 256, 0, stream>>>(
        VP, patchW_t, X, nullptr, patch_b, nullptr, 6272, 512, 768, 1);

    for (int l = 0; l < 12; ++l) {
        // ---- time attention ----
        layernorm_k<<<MR/4, 256, 0, stream>>>(X, XN, ln_t_g + l*DM, ln_t_b + l*DM);
        gemm_mfma<<<dim3(12, 50), 256, 0, stream>>>(
            XN, tqkv_t + (size_t)l*786432, nullptr, QKV, nullptr, nullptr, MR, 1536, 512, 0, 0,
            fsin, fcos, KR, 0);
        sp_part_k<<<dim3(32, SPCH), 256, 0, stream>>>(QKV, PART);
        sp_red_k<<<64, 64, 0, stream>>>(PART, AO);
        attn_time_k<<<392, 128, 0, stream>>>(QKV, KR, AO);
        gemm_mfma64<<<dim3(4, 99), 256, 0, stream>>>(
            AO, toutW_t + (size_t)l*262144, X, nullptr, t_outb + l*DM, X, MR, 512, 512, 0);

        // ---- space attention ----
        layernorm_k<<<MR/4, 256, 0, stream>>>(X, XN, ln_s_g + l*DM, ln_s_b + l*DM);
        gemm_mfma<<<dim3(12, 50), 256, 0, stream>>>(
            XN, sqkv_t + (size_t)l*786432, nullptr, QKV, nullptr, nullptr, MR, 1536, 512, 0, 0,
            isin, icos, KR, 1);
        sp_part_k<<<dim3(32, SPCH), 256, 0, stream>>>(QKV, PART);
        sp_red_k<<<64, 64, 0, stream>>>(PART, AO);
        attn_space_k<<<dim3(256, 4), 256, 0, stream>>>(QKV, KR, AO);
        gemm_mfma64<<<dim3(4, 99), 256, 0, stream>>>(
            AO, soutW_t + (size_t)l*262144, X, nullptr, s_outb + l*DM, X, MR, 512, 512, 0);

        // ---- GEGLU FF (gelu fused into FF1 epilogue via permuted W1) ----
        layernorm_k<<<MR/4, 256, 0, stream>>>(X, XN, ln_f_g + l*DM, ln_f_b + l*DM);
        gemm_mfma<<<dim3(32, 50), 256, 0, stream>>>(
            XN, ffW1_t + (size_t)l*2097152, nullptr, B2, ff_b1 + (size_t)l*4096, nullptr, MR, 4096, 512, 0, 1,
            nullptr, nullptr, nullptr, -1);
        gemm_mfma64<<<dim3(4, 99), 256, 0, stream>>>(
            B2, ffW2_t + (size_t)l*1048576, X, nullptr, ff_b2 + l*DM, X, MR, 512, 2048, 0);
    }

    final_head_k<<<NB, 256, 0, stream>>>(X, out_ln_g, out_ln_b, out_W, out_b, (float*)d_out);
}